// Round 4
// baseline (963.611 us; speedup 1.0000x reference)
//
#include <hip/hip_runtime.h>

// ---------------------------------------------------------------------------
// HypER pipeline on MI355X. B=8192, D=400, OC=32, FW=9, J=392, R=288,
// FCLEN=12544.
//   M    = W_E @ fc1_w.T            (400x288)      prep_M
//   head = bf16(UE[ht0]) @ bf16(W_E) + bn0 stats   gemm_s1<80> (fused)
//   k    = bf16(UE[ht1]) @ bf16(M) + fc1_b         gemm_s1<96>
//   bn0 finalize -> a0,b0                          bn0_fin
//   conv[b,o,j] -> bf16 convb + per-ch stats       conv_k (reg sliding window)
//   bn1 -> alpha,beta; fold into fc_w              bn1_fin, prep_fcw
//   pre  = convb @ Bprep^T  (split-K=4)            fc_gemm_sk:
//          A: LDS dbuf via global_load_lds+XOR swz; B: reg-prefetch from L2/L3
//          2 waves of 64x80 (mi4 x nb5), 1 barrier/step, vmcnt(0) after MFMA
//   reduce partials + bias + bn2 partial stats     reduce_bn2
//   bn2 finalize + relu                            bn2_fin, final_k
// ---------------------------------------------------------------------------

#define BB   8192
#define DD   400
#define RR   288
#define OCC  32
#define FWW  9
#define JJ   392
#define FCLEN 12544
#define KSPL 4
#define KS   (FCLEN / KSPL)   /* 3136 */
#define KSTEPS (KS / 64)      /* 49 */
#define EPSF 1e-5

typedef __attribute__((ext_vector_type(8))) short bf16x8;
typedef __attribute__((ext_vector_type(4))) float f32x4;

__device__ inline unsigned short f2bf(float f) {
    union { float f; unsigned u; } x; x.f = f;
    unsigned r = x.u + 0x7fffu + ((x.u >> 16) & 1u);
    return (unsigned short)(r >> 16);
}

__device__ inline void gload16(const void* g, void* l) {
    __builtin_amdgcn_global_load_lds((const __attribute__((address_space(1))) unsigned int*)g,
                                     (__attribute__((address_space(3))) unsigned int*)l, 16, 0, 0);
}

__device__ inline float block_reduce_256(float v, float* red) {
    #pragma unroll
    for (int m = 1; m < 64; m <<= 1) v += __shfl_xor(v, m);
    int wv = threadIdx.x >> 6;
    if ((threadIdx.x & 63) == 0) red[wv] = v;
    __syncthreads();
    float r = 0.f;
    if (threadIdx.x == 0) r = red[0] + red[1] + red[2] + red[3];
    return r;
}

// ---------------- prep_M: M[i][r] = sum_d W_E[i][d]*fc1_w[r][d] ------------
__global__ __launch_bounds__(256) void prep_M(const float* __restrict__ WE,
                                              const float* __restrict__ f1w,
                                              float* __restrict__ Mout) {
    __shared__ float sA[16][17];
    __shared__ float sB[16][17];
    int tx = threadIdx.x, ty = threadIdx.y;
    int r0 = blockIdx.x * 16, i0 = blockIdx.y * 16;
    float acc = 0.f;
    for (int d0 = 0; d0 < DD; d0 += 16) {
        sA[ty][tx] = WE[(size_t)(i0 + ty) * DD + d0 + tx];
        sB[ty][tx] = f1w[(size_t)(r0 + ty) * DD + d0 + tx];
        __syncthreads();
        #pragma unroll
        for (int dd = 0; dd < 16; ++dd) acc = fmaf(sA[ty][dd], sB[tx][dd], acc);
        __syncthreads();
    }
    Mout[(size_t)(i0 + ty) * RR + r0 + tx] = acc;
}

// ------------- stage-1 gathered GEMM, T14 async-stage pipeline -------------
// Optionally emits per-block partial (sum, sumsq) of outputs for bn0.
template <int BN>
__global__ __launch_bounds__(256) void gemm_s1(const float* __restrict__ A,
                                               const int* __restrict__ idx,
                                               const float* __restrict__ Bm,
                                               const float* __restrict__ bias,
                                               float* __restrict__ C, int N,
                                               float* __restrict__ bn0part) {
    constexpr int BNF = BN / 16;
    constexpr int BCH = 64 * (BN / 4) / 256;   // B float4-chunks per thread
    __shared__ unsigned short Al[64][72];
    __shared__ unsigned short Bl[BN][72];
    __shared__ int ridx[64];
    __shared__ float red[8];
    int tid = threadIdx.x;
    int bm = blockIdx.x, bn = blockIdx.y;
    if (tid < 64) ridx[tid] = idx[bm * 64 + tid];
    int lane = tid & 63, wv = tid >> 6;
    int m16 = lane & 15, kb = lane >> 4;
    f32x4 acc[BNF];
    #pragma unroll
    for (int nb = 0; nb < BNF; ++nb) acc[nb] = (f32x4){0.f, 0.f, 0.f, 0.f};
    __syncthreads();

    float4 av[4];
    float4 bv[BCH];
    auto LOADR = [&](int k0) {
        #pragma unroll
        for (int r = 0; r < 4; ++r) {
            int c = tid + 256 * r;
            int row = c >> 4, kq = c & 15;
            int gk = k0 + kq * 4;
            av[r] = (float4){0.f, 0.f, 0.f, 0.f};
            if (gk < DD) av[r] = *(const float4*)(A + (size_t)ridx[row] * DD + gk);
        }
        #pragma unroll
        for (int r = 0; r < BCH; ++r) {
            int c = tid + 256 * r;
            int kk2 = c / (BN / 4), nq = c % (BN / 4);
            int gk = k0 + kk2;
            bv[r] = (float4){0.f, 0.f, 0.f, 0.f};
            if (gk < DD) bv[r] = *(const float4*)(Bm + (size_t)gk * N + bn * BN + nq * 4);
        }
    };
    auto WRITELDS = [&]() {
        #pragma unroll
        for (int r = 0; r < 4; ++r) {
            int c = tid + 256 * r;
            int row = c >> 4, kq = c & 15;
            ushort4 p;
            p.x = f2bf(av[r].x); p.y = f2bf(av[r].y); p.z = f2bf(av[r].z); p.w = f2bf(av[r].w);
            *(ushort4*)&Al[row][kq * 4] = p;
        }
        #pragma unroll
        for (int r = 0; r < BCH; ++r) {
            int c = tid + 256 * r;
            int kk2 = c / (BN / 4), nq = c % (BN / 4);
            Bl[nq * 4 + 0][kk2] = f2bf(bv[r].x);
            Bl[nq * 4 + 1][kk2] = f2bf(bv[r].y);
            Bl[nq * 4 + 2][kk2] = f2bf(bv[r].z);
            Bl[nq * 4 + 3][kk2] = f2bf(bv[r].w);
        }
    };

    LOADR(0);
    for (int kt = 0; kt < 7; ++kt) {
        WRITELDS();
        __syncthreads();
        if (kt + 1 < 7) LOADR((kt + 1) * 64);   // latency hides under MFMA
        #pragma unroll
        for (int ks = 0; ks < 2; ++ks) {
            bf16x8 a = *(const bf16x8*)&Al[wv * 16 + m16][ks * 32 + kb * 8];
            #pragma unroll
            for (int nb = 0; nb < BNF; ++nb) {
                bf16x8 b = *(const bf16x8*)&Bl[nb * 16 + m16][ks * 32 + kb * 8];
                acc[nb] = __builtin_amdgcn_mfma_f32_16x16x32_bf16(a, b, acc[nb], 0, 0, 0);
            }
        }
        __syncthreads();
    }
    float s1 = 0.f, s2 = 0.f;
    #pragma unroll
    for (int nb = 0; nb < BNF; ++nb)
        #pragma unroll
        for (int rr = 0; rr < 4; ++rr) {
            int gr = bm * 64 + wv * 16 + kb * 4 + rr;
            int gc = bn * BN + nb * 16 + m16;
            float v = acc[nb][rr];
            if (bias) v += bias[gc];
            C[(size_t)gr * N + gc] = v;
            s1 += v; s2 = fmaf(v, v, s2);
        }
    if (bn0part) {
        float t1 = block_reduce_256(s1, red);
        __syncthreads();
        float t2 = block_reduce_256(s2, red);
        if (tid == 0) {
            int pid = bm * gridDim.y + bn;
            bn0part[pid * 2] = t1; bn0part[pid * 2 + 1] = t2;
        }
    }
}

// ---------------- bn0 finalize over 640 block partials ---------------------
__global__ __launch_bounds__(256) void bn0_fin(const float* __restrict__ part,
                                               const float* __restrict__ g,
                                               const float* __restrict__ b,
                                               float* __restrict__ ab0) {
    __shared__ float red[8];
    float s1 = 0.f, s2 = 0.f;
    for (int i = threadIdx.x; i < 640; i += 256) {
        s1 += part[i * 2]; s2 += part[i * 2 + 1];
    }
    float t1 = block_reduce_256(s1, red);
    __syncthreads();
    float t2 = block_reduce_256(s2, red);
    if (threadIdx.x == 0) {
        double n = (double)BB * DD;
        double mean = (double)t1 / n;
        double var = (double)t2 / n - mean * mean;
        float a0 = (float)((double)g[0] / sqrt(var + EPSF));
        float b0 = (float)((double)b[0] - mean * a0);
        ab0[0] = a0; ab0[1] = b0;
    }
}

// ------ per-sample conv: sliding window in regs, wave owns 8 channels ------
__global__ __launch_bounds__(256) void conv_k(const float* __restrict__ head,
                                              const float* __restrict__ kbuf,
                                              const float* __restrict__ ab0,
                                              unsigned short* __restrict__ convb,
                                              float* __restrict__ chpartT) {
    __shared__ float xs[DD];
    __shared__ float ks[RR];
    int b = blockIdx.x, tid = threadIdx.x;
    float a0 = ab0[0], b0 = ab0[1];
    for (int i = tid; i < DD; i += 256) xs[i] = fmaf(head[(size_t)b * DD + i], a0, b0);
    for (int i = tid; i < RR; i += 256) ks[i] = kbuf[(size_t)b * RR + i];
    __syncthreads();
    int lane = tid & 63, wv = tid >> 6;
    unsigned short* orow = convb + (size_t)b * FCLEN;
    float kk[8][FWW];
    #pragma unroll
    for (int oi = 0; oi < 8; ++oi)
        #pragma unroll
        for (int w2 = 0; w2 < FWW; ++w2) kk[oi][w2] = ks[(wv * 8 + oi) * FWW + w2];
    float s1[8], s2[8];
    #pragma unroll
    for (int oi = 0; oi < 8; ++oi) { s1[oi] = 0.f; s2[oi] = 0.f; }
    #pragma unroll
    for (int jt = 0; jt < 2; ++jt) {
        int j0 = jt * 256 + lane * 4;
        if (j0 < JJ) {
            const float4* x4 = (const float4*)xs;
            float4 va = x4[(j0 >> 2)], vb = x4[(j0 >> 2) + 1], vc = x4[(j0 >> 2) + 2];
            float x[12] = {va.x, va.y, va.z, va.w, vb.x, vb.y, vb.z, vb.w, vc.x, vc.y, vc.z, vc.w};
            #pragma unroll
            for (int oi = 0; oi < 8; ++oi) {
                float acc[4];
                #pragma unroll
                for (int q = 0; q < 4; ++q) {
                    float a = 0.f;
                    #pragma unroll
                    for (int w2 = 0; w2 < FWW; ++w2) a = fmaf(x[q + w2], kk[oi][w2], a);
                    acc[q] = a;
                }
                ushort4 p;
                p.x = f2bf(acc[0]); p.y = f2bf(acc[1]); p.z = f2bf(acc[2]); p.w = f2bf(acc[3]);
                *(ushort4*)(orow + (wv * 8 + oi) * JJ + j0) = p;
                #pragma unroll
                for (int q = 0; q < 4; ++q) { s1[oi] += acc[q]; s2[oi] = fmaf(acc[q], acc[q], s2[oi]); }
            }
        }
    }
    #pragma unroll
    for (int oi = 0; oi < 8; ++oi) {
        float a = s1[oi], c = s2[oi];
        #pragma unroll
        for (int m = 1; m < 64; m <<= 1) { a += __shfl_xor(a, m); c += __shfl_xor(c, m); }
        if (lane == 0) {
            int o = wv * 8 + oi;
            chpartT[(size_t)o * BB + b] = a;
            chpartT[(size_t)(OCC + o) * BB + b] = c;
        }
    }
}

__global__ __launch_bounds__(256) void bn1_fin(const float* __restrict__ chpartT,
                                               const float* __restrict__ g1,
                                               const float* __restrict__ b1,
                                               float* __restrict__ alphabeta) {
    __shared__ float red[8];
    int o = blockIdx.x, tid = threadIdx.x;
    float s1 = 0.f, s2 = 0.f;
    for (int t = tid; t < BB; t += 256) {
        s1 += chpartT[(size_t)o * BB + t];
        s2 += chpartT[(size_t)(OCC + o) * BB + t];
    }
    float t1 = block_reduce_256(s1, red);
    __syncthreads();
    float t2 = block_reduce_256(s2, red);
    if (tid == 0) {
        double n = (double)BB * JJ;
        double mean = (double)t1 / n;
        double var = (double)t2 / n - mean * mean;
        float al = (float)((double)g1[o] / sqrt(var + EPSF));
        float be = (float)((double)b1[o] - mean * al);
        alphabeta[o] = al; alphabeta[OCC + o] = be;
    }
}

// ------- fold bn1 into fc_w: Bprep = bf16(fc_w*alpha); bias2 ---------------
__global__ __launch_bounds__(256) void prep_fcw(const float* __restrict__ fc_w,
                                                const float* __restrict__ fc_b,
                                                const float* __restrict__ alphabeta,
                                                unsigned short* __restrict__ Bp,
                                                float* __restrict__ bias2) {
    __shared__ float al[OCC], be[OCC];
    __shared__ float red[8];
    int d = blockIdx.x, tid = threadIdx.x;
    if (tid < OCC) { al[tid] = alphabeta[tid]; be[tid] = alphabeta[OCC + tid]; }
    __syncthreads();
    const float* row = fc_w + (size_t)d * FCLEN;
    unsigned short* orow = Bp + (size_t)d * FCLEN;
    float bacc = 0.f;
    for (int o = 0; o < OCC; ++o) {
        float a = al[o], bb = be[o];
        for (int j = tid; j < JJ; j += 256) {
            float wv = row[o * JJ + j];
            orow[o * JJ + j] = f2bf(wv * a);
            bacc = fmaf(wv, bb, bacc);
        }
    }
    float t = block_reduce_256(bacc, red);
    if (tid == 0) bias2[d] = fc_b[d] + t;
}

// -------- big FC GEMM, split-K=4 -------------------------------------------
// 128 threads = 2 waves, each computing 64x80 (mi=4 x nb=5).
// A: LDS double-buffer (2x16KB) via global_load_lds, XOR-swizzled both sides.
// B: register double-buffer, direct global loads (L2/L3-resident), T14 split.
// One barrier per K-step; vmcnt(0) only after the MFMA cluster.
__global__ __launch_bounds__(128, 2) void fc_gemm_sk(const unsigned short* __restrict__ A,
                                                     const unsigned short* __restrict__ Bp,
                                                     float* __restrict__ P) {
    __shared__ __align__(16) unsigned short Al[2][128 * 64];   // 2 x 16 KiB
    int tid = threadIdx.x;
    int bm = blockIdx.x, bn = blockIdx.y, bz = blockIdx.z;
    int lane = tid & 63, wv = tid >> 6;
    int m16 = lane & 15, kb = lane >> 4;
    f32x4 acc[4][5];
    #pragma unroll
    for (int mi = 0; mi < 4; ++mi)
        #pragma unroll
        for (int nb = 0; nb < 5; ++nb) acc[mi][nb] = (f32x4){0.f, 0.f, 0.f, 0.f};

    // per-lane pre-swizzled global source for A staging (chunk = 1KB = 8 rows)
    const unsigned short* Asrc = A + (size_t)(bm * 128 + (lane >> 3)) * FCLEN
                                   + (size_t)bz * KS + (((lane & 7) ^ (lane >> 3)) << 3);
    const unsigned short* Bbase = Bp + (size_t)bz * KS;

    bf16x8 Bc[10], Bn[10];

#define STAGEA(t, buf) { \
    const unsigned short* ab_ = Asrc + (size_t)(t) * 64; \
    _Pragma("unroll") \
    for (int i_ = 0; i_ < 8; ++i_) { \
        int c_ = wv * 8 + i_; \
        gload16(ab_ + (size_t)c_ * 8 * FCLEN, &Al[buf][c_ * 512]); \
    } }

#define LOADB(t, Barr) { \
    const unsigned short* bb_ = Bbase + (size_t)(t) * 64 + kb * 8; \
    _Pragma("unroll") \
    for (int nb_ = 0; nb_ < 5; ++nb_) { \
        const unsigned short* bc_ = bb_ + (size_t)(bn * 80 + nb_ * 16 + m16) * FCLEN; \
        Barr[nb_ * 2 + 0] = *(const bf16x8*)(bc_); \
        Barr[nb_ * 2 + 1] = *(const bf16x8*)(bc_ + 32); \
    } }

#define MFMA_STEP(buf, Barr) { \
    const unsigned short* Ac_ = &Al[buf][0]; \
    _Pragma("unroll") \
    for (int ks_ = 0; ks_ < 2; ++ks_) { \
        bf16x8 a_[4]; \
        _Pragma("unroll") \
        for (int mi_ = 0; mi_ < 4; ++mi_) { \
            int row_ = wv * 64 + mi_ * 16 + m16; \
            a_[mi_] = *(const bf16x8*)(Ac_ + row_ * 64 + (((ks_ * 4 + kb) ^ (m16 & 7)) << 3)); \
        } \
        _Pragma("unroll") \
        for (int nb_ = 0; nb_ < 5; ++nb_) { \
            bf16x8 b_ = Barr[nb_ * 2 + ks_]; \
            _Pragma("unroll") \
            for (int mi_ = 0; mi_ < 4; ++mi_) \
                acc[mi_][nb_] = __builtin_amdgcn_mfma_f32_16x16x32_bf16(a_[mi_], b_, acc[mi_][nb_], 0, 0, 0); \
        } \
    } }

#define SYNC_STEP() { \
    asm volatile("s_waitcnt vmcnt(0)" ::: "memory"); \
    __builtin_amdgcn_s_barrier(); \
    __builtin_amdgcn_sched_barrier(0); }

    STAGEA(0, 0);
    LOADB(0, Bc);
    SYNC_STEP();

    for (int t = 0; t < KSTEPS; ) {
        if (t + 1 < KSTEPS) { STAGEA(t + 1, 1); LOADB(t + 1, Bn); }
        __builtin_amdgcn_s_setprio(1);
        MFMA_STEP(0, Bc);
        __builtin_amdgcn_s_setprio(0);
        SYNC_STEP();
        ++t; if (t == KSTEPS) break;
        if (t + 1 < KSTEPS) { STAGEA(t + 1, 0); LOADB(t + 1, Bc); }
        __builtin_amdgcn_s_setprio(1);
        MFMA_STEP(1, Bn);
        __builtin_amdgcn_s_setprio(0);
        SYNC_STEP();
        ++t;
    }
#undef STAGEA
#undef LOADB
#undef MFMA_STEP
#undef SYNC_STEP

    float* Po = P + (size_t)bz * BB * DD;
    #pragma unroll
    for (int mi = 0; mi < 4; ++mi)
        #pragma unroll
        for (int nb = 0; nb < 5; ++nb)
            #pragma unroll
            for (int rr = 0; rr < 4; ++rr) {
                int gr = bm * 128 + wv * 64 + mi * 16 + kb * 4 + rr;
                int gc = bn * 80 + nb * 16 + m16;
                Po[(size_t)gr * DD + gc] = acc[mi][nb][rr];
            }
}

// ------ reduce split-K partials + bias, emit bn2 per-column partials -------
__global__ __launch_bounds__(256) void reduce_bn2(const float* __restrict__ P,
                                                  const float* __restrict__ bias2,
                                                  float* __restrict__ out,
                                                  float* __restrict__ part) {
    int blk = blockIdx.x, tid = threadIdx.x;   // 128 blocks x 64 rows
    int r0 = blk * 64;
    const size_t S = (size_t)BB * DD;
    bool hasb = tid < DD - 256;
    float bia = bias2[tid];
    float bib = hasb ? bias2[256 + tid] : 0.f;
    float s1a = 0.f, s2a = 0.f, s1b = 0.f, s2b = 0.f;
    for (int r = 0; r < 64; ++r) {
        size_t base = (size_t)(r0 + r) * DD;
        float v = P[base + tid] + P[S + base + tid] + P[2 * S + base + tid] + P[3 * S + base + tid] + bia;
        out[base + tid] = v;
        s1a += v; s2a = fmaf(v, v, s2a);
        if (hasb) {
            size_t b2i = base + 256 + tid;
            float u = P[b2i] + P[S + b2i] + P[2 * S + b2i] + P[3 * S + b2i] + bib;
            out[b2i] = u;
            s1b += u; s2b = fmaf(u, u, s2b);
        }
    }
    float* p = part + (size_t)blk * (DD * 2);
    p[tid * 2] = s1a; p[tid * 2 + 1] = s2a;
    if (hasb) { p[(256 + tid) * 2] = s1b; p[(256 + tid) * 2 + 1] = s2b; }
}

__global__ __launch_bounds__(128) void bn2_fin(const float* __restrict__ part,
                                               const float* __restrict__ g2,
                                               const float* __restrict__ b2,
                                               float* __restrict__ sc,
                                               float* __restrict__ sh) {
    __shared__ float red[4];
    int col = blockIdx.x, tid = threadIdx.x;
    float s1 = part[(size_t)tid * (DD * 2) + col * 2];
    float s2 = part[(size_t)tid * (DD * 2) + col * 2 + 1];
    #pragma unroll
    for (int m = 1; m < 64; m <<= 1) { s1 += __shfl_xor(s1, m); s2 += __shfl_xor(s2, m); }
    int wv = tid >> 6;
    if ((tid & 63) == 0) { red[wv] = s1; red[2 + wv] = s2; }
    __syncthreads();
    if (tid == 0) {
        double t1 = (double)red[0] + red[1];
        double t2 = (double)red[2] + red[3];
        double mean = t1 / (double)BB;
        double var = t2 / (double)BB - mean * mean;
        float s = (float)((double)g2[col] / sqrt(var + EPSF));
        sc[col] = s;
        sh[col] = (float)((double)b2[col] - mean * s);
    }
}

__global__ __launch_bounds__(256) void final_k(float* __restrict__ out,
                                               const float* __restrict__ sc,
                                               const float* __restrict__ sh) {
    __shared__ float lsc[DD], lsh[DD];
    int tid = threadIdx.x;
    for (int c = tid; c < DD; c += 256) { lsc[c] = sc[c]; lsh[c] = sh[c]; }
    __syncthreads();
    size_t base = (size_t)blockIdx.x * 4 * DD;
    for (int r = 0; r < 4; ++r)
        for (int c = tid; c < DD; c += 256) {
            size_t i = base + (size_t)r * DD + c;
            float v = fmaf(out[i], lsc[c], lsh[c]);
            out[i] = v > 0.f ? v : 0.f;
        }
}

// ---------------------------------------------------------------------------
extern "C" void kernel_launch(void* const* d_in, const int* in_sizes, int n_in,
                              void* d_out, int out_size, void* d_ws, size_t ws_size,
                              hipStream_t stream) {
    const int* ht      = (const int*)d_in[0];
    const float* UE    = (const float*)d_in[1];
    const float* W_E   = (const float*)d_in[2];
    const float* fc1_w = (const float*)d_in[3];
    const float* fc1_b = (const float*)d_in[4];
    const float* fc_w  = (const float*)d_in[5];
    const float* fc_b  = (const float*)d_in[6];
    const float* bn0_g = (const float*)d_in[7];
    const float* bn0_b = (const float*)d_in[8];
    const float* bn1_g = (const float*)d_in[9];
    const float* bn1_b = (const float*)d_in[10];
    const float* bn2_g = (const float*)d_in[11];
    const float* bn2_b = (const float*)d_in[12];
    float* out = (float*)d_out;

    char* w = (char*)d_ws;
    unsigned short* convb = (unsigned short*)w; w += (size_t)BB * FCLEN * 2;      // 205.5 MB
    unsigned short* Bprep = (unsigned short*)w; w += (size_t)DD * FCLEN * 2;      // 10 MB
    float* chpartT = (float*)w; w += (size_t)2 * OCC * BB * 4;                    // 2.1 MB
    float* bn0p = (float*)w;  w += 640 * 2 * 4;
    float* ab0 = (float*)w;   w += 64;
    float* alphabeta = (float*)w; w += 64 * 4;
    float* bias2 = (float*)w; w += DD * 4;
    float* bn2p = (float*)w;  w += (size_t)128 * DD * 2 * 4;
    float* bn2sc = (float*)w; w += DD * 4;
    float* bn2sh = (float*)w; w += DD * 4;
    // split-K partial region (52.4 MB), aliased over head/kbuf/Mbuf (dead by
    // the time fc_gemm_sk runs):
    float* P = (float*)w;     w += (size_t)KSPL * BB * DD * 4;
    float* head = P;                      // 13.1 MB, consumed by conv_k
    float* kbuf = head + (size_t)BB * DD; // 9.4 MB, consumed by conv_k
    float* Mbuf = kbuf + (size_t)BB * RR; // 0.46 MB, consumed by gemm_s1<96>
    (void)ws_size; (void)in_sizes; (void)n_in; (void)out_size;

    prep_M<<<dim3(RR / 16, DD / 16), dim3(16, 16), 0, stream>>>(W_E, fc1_w, Mbuf);
    gemm_s1<80><<<dim3(BB / 64, DD / 80), 256, 0, stream>>>(UE, ht, W_E, nullptr, head, DD, bn0p);
    gemm_s1<96><<<dim3(BB / 64, RR / 96), 256, 0, stream>>>(UE, ht + BB, Mbuf, fc1_b, kbuf, RR, nullptr);
    bn0_fin<<<1, 256, 0, stream>>>(bn0p, bn0_g, bn0_b, ab0);
    conv_k<<<BB, 256, 0, stream>>>(head, kbuf, ab0, convb, chpartT);
    bn1_fin<<<OCC, 256, 0, stream>>>(chpartT, bn1_g, bn1_b, alphabeta);
    prep_fcw<<<DD, 256, 0, stream>>>(fc_w, fc_b, alphabeta, Bprep, bias2);
    fc_gemm_sk<<<dim3(BB / 128, DD / 80, KSPL), 128, 0, stream>>>(convb, Bprep, P);
    reduce_bn2<<<128, 256, 0, stream>>>(P, bias2, out, bn2p);
    bn2_fin<<<DD, 128, 0, stream>>>(bn2p, bn2_g, bn2_b, bn2sc, bn2sh);
    final_k<<<2048, 256, 0, stream>>>(out, bn2sc, bn2sh);
}

// Round 5
// 359.218 us; speedup vs baseline: 2.6825x; 2.6825x over previous
//
#include <hip/hip_runtime.h>

// ---------------------------------------------------------------------------
// HypER pipeline on MI355X. B=8192, D=400, OC=32, FW=9, J=392, R=288,
// FCLEN=12544.
//   M    = W_E @ fc1_w.T            (400x288)      prep_M
//   head = bf16(UE[ht0]) @ bf16(W_E) + bn0 stats   gemm_s1<80> (fused)
//   k    = bf16(UE[ht1]) @ bf16(M) + fc1_b         gemm_s1<96>
//   bn0 finalize -> a0,b0                          bn0_fin
//   conv[b,o,j] -> bf16 convb + per-ch stats       conv_k (reg sliding window)
//   bn1 -> alpha,beta; fold into fc_w              bn1_fin, prep_fcw
//   pre  = convb @ Bprep^T  (split-K=4)            fc_gemm_sk:
//          BM=256 BN=80, 4 waves x (64x80), single-buffer LDS 43KB,
//          global_load_lds + both-sides XOR swizzle, 3 blocks/CU
//   reduce partials + bias + bn2 partial stats     reduce_bn2
//   bn2 finalize + relu                            bn2_fin, final_k
// ---------------------------------------------------------------------------

#define BB   8192
#define DD   400
#define RR   288
#define OCC  32
#define FWW  9
#define JJ   392
#define FCLEN 12544
#define KSPL 4
#define KS   (FCLEN / KSPL)   /* 3136 */
#define KSTEPS (KS / 64)      /* 49 */
#define EPSF 1e-5

typedef __attribute__((ext_vector_type(8))) short bf16x8;
typedef __attribute__((ext_vector_type(4))) float f32x4;

__device__ inline unsigned short f2bf(float f) {
    union { float f; unsigned u; } x; x.f = f;
    unsigned r = x.u + 0x7fffu + ((x.u >> 16) & 1u);
    return (unsigned short)(r >> 16);
}

__device__ inline void gload16(const void* g, void* l) {
    __builtin_amdgcn_global_load_lds((const __attribute__((address_space(1))) unsigned int*)g,
                                     (__attribute__((address_space(3))) unsigned int*)l, 16, 0, 0);
}

__device__ inline float block_reduce_256(float v, float* red) {
    #pragma unroll
    for (int m = 1; m < 64; m <<= 1) v += __shfl_xor(v, m);
    int wv = threadIdx.x >> 6;
    if ((threadIdx.x & 63) == 0) red[wv] = v;
    __syncthreads();
    float r = 0.f;
    if (threadIdx.x == 0) r = red[0] + red[1] + red[2] + red[3];
    return r;
}

// ---------------- prep_M: M[i][r] = sum_d W_E[i][d]*fc1_w[r][d] ------------
__global__ __launch_bounds__(256) void prep_M(const float* __restrict__ WE,
                                              const float* __restrict__ f1w,
                                              float* __restrict__ Mout) {
    __shared__ float sA[16][17];
    __shared__ float sB[16][17];
    int tx = threadIdx.x, ty = threadIdx.y;
    int r0 = blockIdx.x * 16, i0 = blockIdx.y * 16;
    float acc = 0.f;
    for (int d0 = 0; d0 < DD; d0 += 16) {
        sA[ty][tx] = WE[(size_t)(i0 + ty) * DD + d0 + tx];
        sB[ty][tx] = f1w[(size_t)(r0 + ty) * DD + d0 + tx];
        __syncthreads();
        #pragma unroll
        for (int dd = 0; dd < 16; ++dd) acc = fmaf(sA[ty][dd], sB[tx][dd], acc);
        __syncthreads();
    }
    Mout[(size_t)(i0 + ty) * RR + r0 + tx] = acc;
}

// ------------- stage-1 gathered GEMM, T14 async-stage pipeline -------------
// Optionally emits per-block partial (sum, sumsq) of outputs for bn0.
template <int BN>
__global__ __launch_bounds__(256) void gemm_s1(const float* __restrict__ A,
                                               const int* __restrict__ idx,
                                               const float* __restrict__ Bm,
                                               const float* __restrict__ bias,
                                               float* __restrict__ C, int N,
                                               float* __restrict__ bn0part) {
    constexpr int BNF = BN / 16;
    constexpr int BCH = 64 * (BN / 4) / 256;   // B float4-chunks per thread
    __shared__ unsigned short Al[64][72];
    __shared__ unsigned short Bl[BN][72];
    __shared__ int ridx[64];
    __shared__ float red[8];
    int tid = threadIdx.x;
    int bm = blockIdx.x, bn = blockIdx.y;
    if (tid < 64) ridx[tid] = idx[bm * 64 + tid];
    int lane = tid & 63, wv = tid >> 6;
    int m16 = lane & 15, kb = lane >> 4;
    f32x4 acc[BNF];
    #pragma unroll
    for (int nb = 0; nb < BNF; ++nb) acc[nb] = (f32x4){0.f, 0.f, 0.f, 0.f};
    __syncthreads();

    float4 av[4];
    float4 bv[BCH];
    auto LOADR = [&](int k0) {
        #pragma unroll
        for (int r = 0; r < 4; ++r) {
            int c = tid + 256 * r;
            int row = c >> 4, kq = c & 15;
            int gk = k0 + kq * 4;
            av[r] = (float4){0.f, 0.f, 0.f, 0.f};
            if (gk < DD) av[r] = *(const float4*)(A + (size_t)ridx[row] * DD + gk);
        }
        #pragma unroll
        for (int r = 0; r < BCH; ++r) {
            int c = tid + 256 * r;
            int kk2 = c / (BN / 4), nq = c % (BN / 4);
            int gk = k0 + kk2;
            bv[r] = (float4){0.f, 0.f, 0.f, 0.f};
            if (gk < DD) bv[r] = *(const float4*)(Bm + (size_t)gk * N + bn * BN + nq * 4);
        }
    };
    auto WRITELDS = [&]() {
        #pragma unroll
        for (int r = 0; r < 4; ++r) {
            int c = tid + 256 * r;
            int row = c >> 4, kq = c & 15;
            ushort4 p;
            p.x = f2bf(av[r].x); p.y = f2bf(av[r].y); p.z = f2bf(av[r].z); p.w = f2bf(av[r].w);
            *(ushort4*)&Al[row][kq * 4] = p;
        }
        #pragma unroll
        for (int r = 0; r < BCH; ++r) {
            int c = tid + 256 * r;
            int kk2 = c / (BN / 4), nq = c % (BN / 4);
            Bl[nq * 4 + 0][kk2] = f2bf(bv[r].x);
            Bl[nq * 4 + 1][kk2] = f2bf(bv[r].y);
            Bl[nq * 4 + 2][kk2] = f2bf(bv[r].z);
            Bl[nq * 4 + 3][kk2] = f2bf(bv[r].w);
        }
    };

    LOADR(0);
    for (int kt = 0; kt < 7; ++kt) {
        WRITELDS();
        __syncthreads();
        if (kt + 1 < 7) LOADR((kt + 1) * 64);   // latency hides under MFMA
        #pragma unroll
        for (int ks = 0; ks < 2; ++ks) {
            bf16x8 a = *(const bf16x8*)&Al[wv * 16 + m16][ks * 32 + kb * 8];
            #pragma unroll
            for (int nb = 0; nb < BNF; ++nb) {
                bf16x8 b = *(const bf16x8*)&Bl[nb * 16 + m16][ks * 32 + kb * 8];
                acc[nb] = __builtin_amdgcn_mfma_f32_16x16x32_bf16(a, b, acc[nb], 0, 0, 0);
            }
        }
        __syncthreads();
    }
    float s1 = 0.f, s2 = 0.f;
    #pragma unroll
    for (int nb = 0; nb < BNF; ++nb)
        #pragma unroll
        for (int rr = 0; rr < 4; ++rr) {
            int gr = bm * 64 + wv * 16 + kb * 4 + rr;
            int gc = bn * BN + nb * 16 + m16;
            float v = acc[nb][rr];
            if (bias) v += bias[gc];
            C[(size_t)gr * N + gc] = v;
            s1 += v; s2 = fmaf(v, v, s2);
        }
    if (bn0part) {
        float t1 = block_reduce_256(s1, red);
        __syncthreads();
        float t2 = block_reduce_256(s2, red);
        if (tid == 0) {
            int pid = bm * gridDim.y + bn;
            bn0part[pid * 2] = t1; bn0part[pid * 2 + 1] = t2;
        }
    }
}

// ---------------- bn0 finalize over 640 block partials ---------------------
__global__ __launch_bounds__(256) void bn0_fin(const float* __restrict__ part,
                                               const float* __restrict__ g,
                                               const float* __restrict__ b,
                                               float* __restrict__ ab0) {
    __shared__ float red[8];
    float s1 = 0.f, s2 = 0.f;
    for (int i = threadIdx.x; i < 640; i += 256) {
        s1 += part[i * 2]; s2 += part[i * 2 + 1];
    }
    float t1 = block_reduce_256(s1, red);
    __syncthreads();
    float t2 = block_reduce_256(s2, red);
    if (threadIdx.x == 0) {
        double n = (double)BB * DD;
        double mean = (double)t1 / n;
        double var = (double)t2 / n - mean * mean;
        float a0 = (float)((double)g[0] / sqrt(var + EPSF));
        float b0 = (float)((double)b[0] - mean * a0);
        ab0[0] = a0; ab0[1] = b0;
    }
}

// ------ per-sample conv: sliding window in regs, wave owns 8 channels ------
__global__ __launch_bounds__(256) void conv_k(const float* __restrict__ head,
                                              const float* __restrict__ kbuf,
                                              const float* __restrict__ ab0,
                                              unsigned short* __restrict__ convb,
                                              float* __restrict__ chpartT) {
    __shared__ float xs[DD];
    __shared__ float ks[RR];
    int b = blockIdx.x, tid = threadIdx.x;
    float a0 = ab0[0], b0 = ab0[1];
    for (int i = tid; i < DD; i += 256) xs[i] = fmaf(head[(size_t)b * DD + i], a0, b0);
    for (int i = tid; i < RR; i += 256) ks[i] = kbuf[(size_t)b * RR + i];
    __syncthreads();
    int lane = tid & 63, wv = tid >> 6;
    unsigned short* orow = convb + (size_t)b * FCLEN;
    float kk[8][FWW];
    #pragma unroll
    for (int oi = 0; oi < 8; ++oi)
        #pragma unroll
        for (int w2 = 0; w2 < FWW; ++w2) kk[oi][w2] = ks[(wv * 8 + oi) * FWW + w2];
    float s1[8], s2[8];
    #pragma unroll
    for (int oi = 0; oi < 8; ++oi) { s1[oi] = 0.f; s2[oi] = 0.f; }
    #pragma unroll
    for (int jt = 0; jt < 2; ++jt) {
        int j0 = jt * 256 + lane * 4;
        if (j0 < JJ) {
            const float4* x4 = (const float4*)xs;
            float4 va = x4[(j0 >> 2)], vb = x4[(j0 >> 2) + 1], vc = x4[(j0 >> 2) + 2];
            float x[12] = {va.x, va.y, va.z, va.w, vb.x, vb.y, vb.z, vb.w, vc.x, vc.y, vc.z, vc.w};
            #pragma unroll
            for (int oi = 0; oi < 8; ++oi) {
                float acc[4];
                #pragma unroll
                for (int q = 0; q < 4; ++q) {
                    float a = 0.f;
                    #pragma unroll
                    for (int w2 = 0; w2 < FWW; ++w2) a = fmaf(x[q + w2], kk[oi][w2], a);
                    acc[q] = a;
                }
                ushort4 p;
                p.x = f2bf(acc[0]); p.y = f2bf(acc[1]); p.z = f2bf(acc[2]); p.w = f2bf(acc[3]);
                *(ushort4*)(orow + (wv * 8 + oi) * JJ + j0) = p;
                #pragma unroll
                for (int q = 0; q < 4; ++q) { s1[oi] += acc[q]; s2[oi] = fmaf(acc[q], acc[q], s2[oi]); }
            }
        }
    }
    #pragma unroll
    for (int oi = 0; oi < 8; ++oi) {
        float a = s1[oi], c = s2[oi];
        #pragma unroll
        for (int m = 1; m < 64; m <<= 1) { a += __shfl_xor(a, m); c += __shfl_xor(c, m); }
        if (lane == 0) {
            int o = wv * 8 + oi;
            chpartT[(size_t)o * BB + b] = a;
            chpartT[(size_t)(OCC + o) * BB + b] = c;
        }
    }
}

__global__ __launch_bounds__(256) void bn1_fin(const float* __restrict__ chpartT,
                                               const float* __restrict__ g1,
                                               const float* __restrict__ b1,
                                               float* __restrict__ alphabeta) {
    __shared__ float red[8];
    int o = blockIdx.x, tid = threadIdx.x;
    float s1 = 0.f, s2 = 0.f;
    for (int t = tid; t < BB; t += 256) {
        s1 += chpartT[(size_t)o * BB + t];
        s2 += chpartT[(size_t)(OCC + o) * BB + t];
    }
    float t1 = block_reduce_256(s1, red);
    __syncthreads();
    float t2 = block_reduce_256(s2, red);
    if (tid == 0) {
        double n = (double)BB * JJ;
        double mean = (double)t1 / n;
        double var = (double)t2 / n - mean * mean;
        float al = (float)((double)g1[o] / sqrt(var + EPSF));
        float be = (float)((double)b1[o] - mean * al);
        alphabeta[o] = al; alphabeta[OCC + o] = be;
    }
}

// ------- fold bn1 into fc_w: Bprep = bf16(fc_w*alpha); bias2 ---------------
__global__ __launch_bounds__(256) void prep_fcw(const float* __restrict__ fc_w,
                                                const float* __restrict__ fc_b,
                                                const float* __restrict__ alphabeta,
                                                unsigned short* __restrict__ Bp,
                                                float* __restrict__ bias2) {
    __shared__ float al[OCC], be[OCC];
    __shared__ float red[8];
    int d = blockIdx.x, tid = threadIdx.x;
    if (tid < OCC) { al[tid] = alphabeta[tid]; be[tid] = alphabeta[OCC + tid]; }
    __syncthreads();
    const float* row = fc_w + (size_t)d * FCLEN;
    unsigned short* orow = Bp + (size_t)d * FCLEN;
    float bacc = 0.f;
    for (int o = 0; o < OCC; ++o) {
        float a = al[o], bb = be[o];
        for (int j = tid; j < JJ; j += 256) {
            float wv = row[o * JJ + j];
            orow[o * JJ + j] = f2bf(wv * a);
            bacc = fmaf(wv, bb, bacc);
        }
    }
    float t = block_reduce_256(bacc, red);
    if (tid == 0) bias2[d] = fc_b[d] + t;
}

// -------- big FC GEMM, split-K=4, BM=256 BN=80, 4 waves x (64x80) ----------
// Single-buffer LDS (43KB -> 3 blocks/CU). A+B staged via global_load_lds
// with both-sides XOR swizzle (linear LDS dest, inverse-swizzled global src,
// swizzled ds_read). Simple barrier loop (R2 structure, better reuse ratio).
__global__ __launch_bounds__(256, 3) void fc_gemm_sk(const unsigned short* __restrict__ A,
                                                     const unsigned short* __restrict__ Bp,
                                                     float* __restrict__ P) {
    __shared__ __align__(16) unsigned short Al[256 * 64];   // 32 KiB, 32 chunks
    __shared__ __align__(16) unsigned short Bl[80 * 64];    // 10 KiB, 10 chunks
    int tid = threadIdx.x;
    int bm = blockIdx.x, bn = blockIdx.y, bz = blockIdx.z;
    int lane = tid & 63, wv = tid >> 6;
    int m16 = lane & 15, kb = lane >> 4;
    int srow = lane >> 3, scol = lane & 7;    // staging lane -> (row-in-chunk, 16B slot)
    int sw = m16 & 7;                          // read-side XOR term (row & 7)
    f32x4 acc[4][5];
    #pragma unroll
    for (int mi = 0; mi < 4; ++mi)
        #pragma unroll
        for (int nb = 0; nb < 5; ++nb) acc[mi][nb] = (f32x4){0.f, 0.f, 0.f, 0.f};

    // per-lane pre-swizzled global sources (chunk = 1KB = 8 rows x 64 cols)
    const unsigned short* Asrc = A + (size_t)(bm * 256 + srow) * FCLEN
                                   + (size_t)bz * KS + ((scol ^ srow) << 3);
    const unsigned short* Bsrc = Bp + (size_t)(bn * 80 + srow) * FCLEN
                                   + (size_t)bz * KS + ((scol ^ srow) << 3);

    for (int kt = 0; kt < KSTEPS; ++kt) {
        const size_t koff = (size_t)kt * 64;
        // 42 chunks total: 32 A + 10 B, wave wv takes chunks wv+4i
        #pragma unroll
        for (int i = 0; i < 11; ++i) {
            int c = wv + i * 4;
            if (c < 32) {
                gload16(Asrc + (size_t)c * 8 * FCLEN + koff, Al + c * 512);
            } else if (c < 42) {
                int cb = c - 32;
                gload16(Bsrc + (size_t)cb * 8 * FCLEN + koff, Bl + cb * 512);
            }
        }
        __syncthreads();
        #pragma unroll
        for (int ks2 = 0; ks2 < 2; ++ks2) {
            int ch = (((ks2 * 4 + kb) ^ sw) << 3);
            bf16x8 a[4];
            #pragma unroll
            for (int mi = 0; mi < 4; ++mi)
                a[mi] = *(const bf16x8*)(Al + (wv * 64 + mi * 16 + m16) * 64 + ch);
            #pragma unroll
            for (int nb = 0; nb < 5; ++nb) {
                bf16x8 b = *(const bf16x8*)(Bl + (nb * 16 + m16) * 64 + ch);
                #pragma unroll
                for (int mi = 0; mi < 4; ++mi)
                    acc[mi][nb] = __builtin_amdgcn_mfma_f32_16x16x32_bf16(a[mi], b, acc[mi][nb], 0, 0, 0);
            }
        }
        __syncthreads();
    }

    float* Po = P + (size_t)bz * BB * DD;
    #pragma unroll
    for (int mi = 0; mi < 4; ++mi)
        #pragma unroll
        for (int nb = 0; nb < 5; ++nb)
            #pragma unroll
            for (int rr = 0; rr < 4; ++rr) {
                int gr = bm * 256 + wv * 64 + mi * 16 + kb * 4 + rr;
                int gc = bn * 80 + nb * 16 + m16;
                Po[(size_t)gr * DD + gc] = acc[mi][nb][rr];
            }
}

// ------ reduce split-K partials + bias, emit bn2 per-column partials -------
__global__ __launch_bounds__(256) void reduce_bn2(const float* __restrict__ P,
                                                  const float* __restrict__ bias2,
                                                  float* __restrict__ out,
                                                  float* __restrict__ part) {
    int blk = blockIdx.x, tid = threadIdx.x;   // 128 blocks x 64 rows
    int r0 = blk * 64;
    const size_t S = (size_t)BB * DD;
    bool hasb = tid < DD - 256;
    float bia = bias2[tid];
    float bib = hasb ? bias2[256 + tid] : 0.f;
    float s1a = 0.f, s2a = 0.f, s1b = 0.f, s2b = 0.f;
    for (int r = 0; r < 64; ++r) {
        size_t base = (size_t)(r0 + r) * DD;
        float v = P[base + tid] + P[S + base + tid] + P[2 * S + base + tid] + P[3 * S + base + tid] + bia;
        out[base + tid] = v;
        s1a += v; s2a = fmaf(v, v, s2a);
        if (hasb) {
            size_t b2i = base + 256 + tid;
            float u = P[b2i] + P[S + b2i] + P[2 * S + b2i] + P[3 * S + b2i] + bib;
            out[b2i] = u;
            s1b += u; s2b = fmaf(u, u, s2b);
        }
    }
    float* p = part + (size_t)blk * (DD * 2);
    p[tid * 2] = s1a; p[tid * 2 + 1] = s2a;
    if (hasb) { p[(256 + tid) * 2] = s1b; p[(256 + tid) * 2 + 1] = s2b; }
}

__global__ __launch_bounds__(128) void bn2_fin(const float* __restrict__ part,
                                               const float* __restrict__ g2,
                                               const float* __restrict__ b2,
                                               float* __restrict__ sc,
                                               float* __restrict__ sh) {
    __shared__ float red[4];
    int col = blockIdx.x, tid = threadIdx.x;
    float s1 = part[(size_t)tid * (DD * 2) + col * 2];
    float s2 = part[(size_t)tid * (DD * 2) + col * 2 + 1];
    #pragma unroll
    for (int m = 1; m < 64; m <<= 1) { s1 += __shfl_xor(s1, m); s2 += __shfl_xor(s2, m); }
    int wv = tid >> 6;
    if ((tid & 63) == 0) { red[wv] = s1; red[2 + wv] = s2; }
    __syncthreads();
    if (tid == 0) {
        double t1 = (double)red[0] + red[1];
        double t2 = (double)red[2] + red[3];
        double mean = t1 / (double)BB;
        double var = t2 / (double)BB - mean * mean;
        float s = (float)((double)g2[col] / sqrt(var + EPSF));
        sc[col] = s;
        sh[col] = (float)((double)b2[col] - mean * s);
    }
}

__global__ __launch_bounds__(256) void final_k(float* __restrict__ out,
                                               const float* __restrict__ sc,
                                               const float* __restrict__ sh) {
    __shared__ float lsc[DD], lsh[DD];
    int tid = threadIdx.x;
    for (int c = tid; c < DD; c += 256) { lsc[c] = sc[c]; lsh[c] = sh[c]; }
    __syncthreads();
    size_t base = (size_t)blockIdx.x * 4 * DD;
    for (int r = 0; r < 4; ++r)
        for (int c = tid; c < DD; c += 256) {
            size_t i = base + (size_t)r * DD + c;
            float v = fmaf(out[i], lsc[c], lsh[c]);
            out[i] = v > 0.f ? v : 0.f;
        }
}

// ---------------------------------------------------------------------------
extern "C" void kernel_launch(void* const* d_in, const int* in_sizes, int n_in,
                              void* d_out, int out_size, void* d_ws, size_t ws_size,
                              hipStream_t stream) {
    const int* ht      = (const int*)d_in[0];
    const float* UE    = (const float*)d_in[1];
    const float* W_E   = (const float*)d_in[2];
    const float* fc1_w = (const float*)d_in[3];
    const float* fc1_b = (const float*)d_in[4];
    const float* fc_w  = (const float*)d_in[5];
    const float* fc_b  = (const float*)d_in[6];
    const float* bn0_g = (const float*)d_in[7];
    const float* bn0_b = (const float*)d_in[8];
    const float* bn1_g = (const float*)d_in[9];
    const float* bn1_b = (const float*)d_in[10];
    const float* bn2_g = (const float*)d_in[11];
    const float* bn2_b = (const float*)d_in[12];
    float* out = (float*)d_out;

    char* w = (char*)d_ws;
    unsigned short* convb = (unsigned short*)w; w += (size_t)BB * FCLEN * 2;      // 205.5 MB
    unsigned short* Bprep = (unsigned short*)w; w += (size_t)DD * FCLEN * 2;      // 10 MB
    float* chpartT = (float*)w; w += (size_t)2 * OCC * BB * 4;                    // 2.1 MB
    float* bn0p = (float*)w;  w += 640 * 2 * 4;
    float* ab0 = (float*)w;   w += 64;
    float* alphabeta = (float*)w; w += 64 * 4;
    float* bias2 = (float*)w; w += DD * 4;
    float* bn2p = (float*)w;  w += (size_t)128 * DD * 2 * 4;
    float* bn2sc = (float*)w; w += DD * 4;
    float* bn2sh = (float*)w; w += DD * 4;
    // split-K partial region (52.4 MB), aliased over head/kbuf/Mbuf (dead by
    // the time fc_gemm_sk runs):
    float* P = (float*)w;     w += (size_t)KSPL * BB * DD * 4;
    float* head = P;                      // 13.1 MB, consumed by conv_k
    float* kbuf = head + (size_t)BB * DD; // 9.4 MB, consumed by conv_k
    float* Mbuf = kbuf + (size_t)BB * RR; // 0.46 MB, consumed by gemm_s1<96>
    (void)ws_size; (void)in_sizes; (void)n_in; (void)out_size;

    prep_M<<<dim3(RR / 16, DD / 16), dim3(16, 16), 0, stream>>>(W_E, fc1_w, Mbuf);
    gemm_s1<80><<<dim3(BB / 64, DD / 80), 256, 0, stream>>>(UE, ht, W_E, nullptr, head, DD, bn0p);
    gemm_s1<96><<<dim3(BB / 64, RR / 96), 256, 0, stream>>>(UE, ht + BB, Mbuf, fc1_b, kbuf, RR, nullptr);
    bn0_fin<<<1, 256, 0, stream>>>(bn0p, bn0_g, bn0_b, ab0);
    conv_k<<<BB, 256, 0, stream>>>(head, kbuf, ab0, convb, chpartT);
    bn1_fin<<<OCC, 256, 0, stream>>>(chpartT, bn1_g, bn1_b, alphabeta);
    prep_fcw<<<DD, 256, 0, stream>>>(fc_w, fc_b, alphabeta, Bprep, bias2);
    fc_gemm_sk<<<dim3(BB / 256, DD / 80, KSPL), 256, 0, stream>>>(convb, Bprep, P);
    reduce_bn2<<<128, 256, 0, stream>>>(P, bias2, out, bn2p);
    bn2_fin<<<DD, 128, 0, stream>>>(bn2p, bn2_g, bn2_b, bn2sc, bn2sh);
    final_k<<<2048, 256, 0, stream>>>(out, bn2sc, bn2sh);
}

// Round 6
// 350.058 us; speedup vs baseline: 2.7527x; 1.0262x over previous
//
#include <hip/hip_runtime.h>

// ---------------------------------------------------------------------------
// HypER pipeline on MI355X. B=8192, D=400, OC=32, FW=9, J=392, R=288,
// FCLEN=12544.
//   M    = W_E @ fc1_w.T            (400x288)      prep_M
//   head = bf16(UE[ht0]) @ bf16(W_E) + bn0 stats   gemm_s1<80> (fused)
//   k    = bf16(UE[ht1]) @ bf16(M) + fc1_b         gemm_s1<96>
//   bn0 finalize -> a0,b0                          bn0_fin
//   conv[b,o,j] -> bf16 convb + per-ch stats       conv_k (reg sliding window)
//   bn1 -> alpha,beta; fold into fc_w              bn1_fin, prep_fcw
//   pre  = convb @ Bprep^T  (split-K=4)            fc_gemm_sk:
//          BM=128 BN=80, 2-phase DOUBLE-BUFFER (stage t+1 under MFMA t,
//          drain after MFMA), global_load_lds + XOR swz, XCD swizzle
//   reduce partials + bias + bn2 partial stats     reduce_bn2 (512 blocks)
//   bn2 finalize + relu                            bn2_fin, final_k
// ---------------------------------------------------------------------------

#define BB   8192
#define DD   400
#define RR   288
#define OCC  32
#define FWW  9
#define JJ   392
#define FCLEN 12544
#define KSPL 4
#define KS   (FCLEN / KSPL)   /* 3136 */
#define KSTEPS (KS / 64)      /* 49 */
#define EPSF 1e-5
#define RB2  512              /* reduce_bn2 blocks */

typedef __attribute__((ext_vector_type(8))) short bf16x8;
typedef __attribute__((ext_vector_type(4))) float f32x4;

__device__ inline unsigned short f2bf(float f) {
    union { float f; unsigned u; } x; x.f = f;
    unsigned r = x.u + 0x7fffu + ((x.u >> 16) & 1u);
    return (unsigned short)(r >> 16);
}

__device__ inline void gload16(const void* g, void* l) {
    __builtin_amdgcn_global_load_lds((const __attribute__((address_space(1))) unsigned int*)g,
                                     (__attribute__((address_space(3))) unsigned int*)l, 16, 0, 0);
}

__device__ inline float block_reduce_256(float v, float* red) {
    #pragma unroll
    for (int m = 1; m < 64; m <<= 1) v += __shfl_xor(v, m);
    int wv = threadIdx.x >> 6;
    if ((threadIdx.x & 63) == 0) red[wv] = v;
    __syncthreads();
    float r = 0.f;
    if (threadIdx.x == 0) r = red[0] + red[1] + red[2] + red[3];
    return r;
}

// ---------------- prep_M: M[i][r] = sum_d W_E[i][d]*fc1_w[r][d] ------------
__global__ __launch_bounds__(256) void prep_M(const float* __restrict__ WE,
                                              const float* __restrict__ f1w,
                                              float* __restrict__ Mout) {
    __shared__ float sA[16][17];
    __shared__ float sB[16][17];
    int tx = threadIdx.x, ty = threadIdx.y;
    int r0 = blockIdx.x * 16, i0 = blockIdx.y * 16;
    float acc = 0.f;
    for (int d0 = 0; d0 < DD; d0 += 16) {
        sA[ty][tx] = WE[(size_t)(i0 + ty) * DD + d0 + tx];
        sB[ty][tx] = f1w[(size_t)(r0 + ty) * DD + d0 + tx];
        __syncthreads();
        #pragma unroll
        for (int dd = 0; dd < 16; ++dd) acc = fmaf(sA[ty][dd], sB[tx][dd], acc);
        __syncthreads();
    }
    Mout[(size_t)(i0 + ty) * RR + r0 + tx] = acc;
}

// ------------- stage-1 gathered GEMM, T14 async-stage pipeline -------------
// Optionally emits per-block partial (sum, sumsq) of outputs for bn0.
template <int BN>
__global__ __launch_bounds__(256) void gemm_s1(const float* __restrict__ A,
                                               const int* __restrict__ idx,
                                               const float* __restrict__ Bm,
                                               const float* __restrict__ bias,
                                               float* __restrict__ C, int N,
                                               float* __restrict__ bn0part) {
    constexpr int BNF = BN / 16;
    constexpr int BCH = 64 * (BN / 4) / 256;   // B float4-chunks per thread
    __shared__ unsigned short Al[64][72];
    __shared__ unsigned short Bl[BN][72];
    __shared__ int ridx[64];
    __shared__ float red[8];
    int tid = threadIdx.x;
    int bm = blockIdx.x, bn = blockIdx.y;
    if (tid < 64) ridx[tid] = idx[bm * 64 + tid];
    int lane = tid & 63, wv = tid >> 6;
    int m16 = lane & 15, kb = lane >> 4;
    f32x4 acc[BNF];
    #pragma unroll
    for (int nb = 0; nb < BNF; ++nb) acc[nb] = (f32x4){0.f, 0.f, 0.f, 0.f};
    __syncthreads();

    float4 av[4];
    float4 bv[BCH];
    auto LOADR = [&](int k0) {
        #pragma unroll
        for (int r = 0; r < 4; ++r) {
            int c = tid + 256 * r;
            int row = c >> 4, kq = c & 15;
            int gk = k0 + kq * 4;
            av[r] = (float4){0.f, 0.f, 0.f, 0.f};
            if (gk < DD) av[r] = *(const float4*)(A + (size_t)ridx[row] * DD + gk);
        }
        #pragma unroll
        for (int r = 0; r < BCH; ++r) {
            int c = tid + 256 * r;
            int kk2 = c / (BN / 4), nq = c % (BN / 4);
            int gk = k0 + kk2;
            bv[r] = (float4){0.f, 0.f, 0.f, 0.f};
            if (gk < DD) bv[r] = *(const float4*)(Bm + (size_t)gk * N + bn * BN + nq * 4);
        }
    };
    auto WRITELDS = [&]() {
        #pragma unroll
        for (int r = 0; r < 4; ++r) {
            int c = tid + 256 * r;
            int row = c >> 4, kq = c & 15;
            ushort4 p;
            p.x = f2bf(av[r].x); p.y = f2bf(av[r].y); p.z = f2bf(av[r].z); p.w = f2bf(av[r].w);
            *(ushort4*)&Al[row][kq * 4] = p;
        }
        #pragma unroll
        for (int r = 0; r < BCH; ++r) {
            int c = tid + 256 * r;
            int kk2 = c / (BN / 4), nq = c % (BN / 4);
            Bl[nq * 4 + 0][kk2] = f2bf(bv[r].x);
            Bl[nq * 4 + 1][kk2] = f2bf(bv[r].y);
            Bl[nq * 4 + 2][kk2] = f2bf(bv[r].z);
            Bl[nq * 4 + 3][kk2] = f2bf(bv[r].w);
        }
    };

    LOADR(0);
    for (int kt = 0; kt < 7; ++kt) {
        WRITELDS();
        __syncthreads();
        if (kt + 1 < 7) LOADR((kt + 1) * 64);   // latency hides under MFMA
        #pragma unroll
        for (int ks = 0; ks < 2; ++ks) {
            bf16x8 a = *(const bf16x8*)&Al[wv * 16 + m16][ks * 32 + kb * 8];
            #pragma unroll
            for (int nb = 0; nb < BNF; ++nb) {
                bf16x8 b = *(const bf16x8*)&Bl[nb * 16 + m16][ks * 32 + kb * 8];
                acc[nb] = __builtin_amdgcn_mfma_f32_16x16x32_bf16(a, b, acc[nb], 0, 0, 0);
            }
        }
        __syncthreads();
    }
    float s1 = 0.f, s2 = 0.f;
    #pragma unroll
    for (int nb = 0; nb < BNF; ++nb)
        #pragma unroll
        for (int rr = 0; rr < 4; ++rr) {
            int gr = bm * 64 + wv * 16 + kb * 4 + rr;
            int gc = bn * BN + nb * 16 + m16;
            float v = acc[nb][rr];
            if (bias) v += bias[gc];
            C[(size_t)gr * N + gc] = v;
            s1 += v; s2 = fmaf(v, v, s2);
        }
    if (bn0part) {
        float t1 = block_reduce_256(s1, red);
        __syncthreads();
        float t2 = block_reduce_256(s2, red);
        if (tid == 0) {
            int pid = bm * gridDim.y + bn;
            bn0part[pid * 2] = t1; bn0part[pid * 2 + 1] = t2;
        }
    }
}

// ---------------- bn0 finalize over 640 block partials ---------------------
__global__ __launch_bounds__(256) void bn0_fin(const float* __restrict__ part,
                                               const float* __restrict__ g,
                                               const float* __restrict__ b,
                                               float* __restrict__ ab0) {
    __shared__ float red[8];
    float s1 = 0.f, s2 = 0.f;
    for (int i = threadIdx.x; i < 640; i += 256) {
        s1 += part[i * 2]; s2 += part[i * 2 + 1];
    }
    float t1 = block_reduce_256(s1, red);
    __syncthreads();
    float t2 = block_reduce_256(s2, red);
    if (threadIdx.x == 0) {
        double n = (double)BB * DD;
        double mean = (double)t1 / n;
        double var = (double)t2 / n - mean * mean;
        float a0 = (float)((double)g[0] / sqrt(var + EPSF));
        float b0 = (float)((double)b[0] - mean * a0);
        ab0[0] = a0; ab0[1] = b0;
    }
}

// ------ per-sample conv: sliding window in regs, wave owns 8 channels ------
__global__ __launch_bounds__(256) void conv_k(const float* __restrict__ head,
                                              const float* __restrict__ kbuf,
                                              const float* __restrict__ ab0,
                                              unsigned short* __restrict__ convb,
                                              float* __restrict__ chpartT) {
    __shared__ float xs[DD];
    __shared__ float ks[RR];
    int b = blockIdx.x, tid = threadIdx.x;
    float a0 = ab0[0], b0 = ab0[1];
    for (int i = tid; i < DD; i += 256) xs[i] = fmaf(head[(size_t)b * DD + i], a0, b0);
    for (int i = tid; i < RR; i += 256) ks[i] = kbuf[(size_t)b * RR + i];
    __syncthreads();
    int lane = tid & 63, wv = tid >> 6;
    unsigned short* orow = convb + (size_t)b * FCLEN;
    float kk[8][FWW];
    #pragma unroll
    for (int oi = 0; oi < 8; ++oi)
        #pragma unroll
        for (int w2 = 0; w2 < FWW; ++w2) kk[oi][w2] = ks[(wv * 8 + oi) * FWW + w2];
    float s1[8], s2[8];
    #pragma unroll
    for (int oi = 0; oi < 8; ++oi) { s1[oi] = 0.f; s2[oi] = 0.f; }
    #pragma unroll
    for (int jt = 0; jt < 2; ++jt) {
        int j0 = jt * 256 + lane * 4;
        if (j0 < JJ) {
            const float4* x4 = (const float4*)xs;
            float4 va = x4[(j0 >> 2)], vb = x4[(j0 >> 2) + 1], vc = x4[(j0 >> 2) + 2];
            float x[12] = {va.x, va.y, va.z, va.w, vb.x, vb.y, vb.z, vb.w, vc.x, vc.y, vc.z, vc.w};
            #pragma unroll
            for (int oi = 0; oi < 8; ++oi) {
                float acc[4];
                #pragma unroll
                for (int q = 0; q < 4; ++q) {
                    float a = 0.f;
                    #pragma unroll
                    for (int w2 = 0; w2 < FWW; ++w2) a = fmaf(x[q + w2], kk[oi][w2], a);
                    acc[q] = a;
                }
                ushort4 p;
                p.x = f2bf(acc[0]); p.y = f2bf(acc[1]); p.z = f2bf(acc[2]); p.w = f2bf(acc[3]);
                *(ushort4*)(orow + (wv * 8 + oi) * JJ + j0) = p;
                #pragma unroll
                for (int q = 0; q < 4; ++q) { s1[oi] += acc[q]; s2[oi] = fmaf(acc[q], acc[q], s2[oi]); }
            }
        }
    }
    #pragma unroll
    for (int oi = 0; oi < 8; ++oi) {
        float a = s1[oi], c = s2[oi];
        #pragma unroll
        for (int m = 1; m < 64; m <<= 1) { a += __shfl_xor(a, m); c += __shfl_xor(c, m); }
        if (lane == 0) {
            int o = wv * 8 + oi;
            chpartT[(size_t)o * BB + b] = a;
            chpartT[(size_t)(OCC + o) * BB + b] = c;
        }
    }
}

__global__ __launch_bounds__(256) void bn1_fin(const float* __restrict__ chpartT,
                                               const float* __restrict__ g1,
                                               const float* __restrict__ b1,
                                               float* __restrict__ alphabeta) {
    __shared__ float red[8];
    int o = blockIdx.x, tid = threadIdx.x;
    float s1 = 0.f, s2 = 0.f;
    for (int t = tid; t < BB; t += 256) {
        s1 += chpartT[(size_t)o * BB + t];
        s2 += chpartT[(size_t)(OCC + o) * BB + t];
    }
    float t1 = block_reduce_256(s1, red);
    __syncthreads();
    float t2 = block_reduce_256(s2, red);
    if (tid == 0) {
        double n = (double)BB * JJ;
        double mean = (double)t1 / n;
        double var = (double)t2 / n - mean * mean;
        float al = (float)((double)g1[o] / sqrt(var + EPSF));
        float be = (float)((double)b1[o] - mean * al);
        alphabeta[o] = al; alphabeta[OCC + o] = be;
    }
}

// ------- fold bn1 into fc_w: Bprep = bf16(fc_w*alpha); bias2 ---------------
__global__ __launch_bounds__(256) void prep_fcw(const float* __restrict__ fc_w,
                                                const float* __restrict__ fc_b,
                                                const float* __restrict__ alphabeta,
                                                unsigned short* __restrict__ Bp,
                                                float* __restrict__ bias2) {
    __shared__ float al[OCC], be[OCC];
    __shared__ float red[8];
    int d = blockIdx.x, tid = threadIdx.x;
    if (tid < OCC) { al[tid] = alphabeta[tid]; be[tid] = alphabeta[OCC + tid]; }
    __syncthreads();
    const float* row = fc_w + (size_t)d * FCLEN;
    unsigned short* orow = Bp + (size_t)d * FCLEN;
    float bacc = 0.f;
    for (int o = 0; o < OCC; ++o) {
        float a = al[o], bb = be[o];
        for (int j = tid; j < JJ; j += 256) {
            float wv = row[o * JJ + j];
            orow[o * JJ + j] = f2bf(wv * a);
            bacc = fmaf(wv, bb, bacc);
        }
    }
    float t = block_reduce_256(bacc, red);
    if (tid == 0) bias2[d] = fc_b[d] + t;
}

// -------- big FC GEMM, split-K=4, BM=128 BN=80, 2-phase double-buffer ------
// stage(t+1) issued BEFORE MFMA(t); __syncthreads() (vmcnt0 drain) lands
// AFTER the MFMA phase has covered the load latency. LDS 2x26KB -> 3 blk/CU.
// global_load_lds with both-sides XOR swizzle; bijective XCD grid swizzle.
__global__ __launch_bounds__(256, 3) void fc_gemm_sk(const unsigned short* __restrict__ A,
                                                     const unsigned short* __restrict__ Bp,
                                                     float* __restrict__ P) {
    __shared__ __align__(16) unsigned short Al[2][128 * 64];   // 2 x 16 KiB
    __shared__ __align__(16) unsigned short Bl[2][80 * 64];    // 2 x 10 KiB
    int tid = threadIdx.x;
    // bijective XCD swizzle: nwg = 1280 = 8 x 160
    int orig = blockIdx.x;
    int wgid = (orig & 7) * 160 + (orig >> 3);
    int bn = wgid % 5;
    int rest = wgid / 5;            // 0..255
    int bm = rest & 63;
    int bz = rest >> 6;
    int lane = tid & 63, wv = tid >> 6;
    int m16 = lane & 15, kb = lane >> 4;
    int srow = lane >> 3, scol = lane & 7;    // staging: (row-in-chunk, 16B slot)
    int sw = m16 & 7;                          // read-side XOR term (row & 7)
    f32x4 acc[2][5];
    #pragma unroll
    for (int mi = 0; mi < 2; ++mi)
        #pragma unroll
        for (int nb = 0; nb < 5; ++nb) acc[mi][nb] = (f32x4){0.f, 0.f, 0.f, 0.f};

    // per-lane pre-swizzled global sources (chunk = 1KB = 8 rows x 64 cols)
    const unsigned short* Asrc = A + (size_t)(bm * 128 + srow) * FCLEN
                                   + (size_t)bz * KS + ((scol ^ srow) << 3);
    const unsigned short* Bsrc = Bp + (size_t)(bn * 80 + srow) * FCLEN
                                   + (size_t)bz * KS + ((scol ^ srow) << 3);

    // 26 chunks: 16 A + 10 B; wave wv takes chunks wv + 4i
    auto STAGE = [&](int t, int buf) {
        const size_t koff = (size_t)t * 64;
        #pragma unroll
        for (int i = 0; i < 7; ++i) {
            int c = wv + i * 4;
            if (c < 16) {
                gload16(Asrc + (size_t)c * 8 * FCLEN + koff, &Al[buf][c * 512]);
            } else if (c < 26) {
                int cb = c - 16;
                gload16(Bsrc + (size_t)cb * 8 * FCLEN + koff, &Bl[buf][cb * 512]);
            }
        }
    };

    STAGE(0, 0);
    __syncthreads();
    for (int t = 0; t < KSTEPS; ++t) {
        if (t + 1 < KSTEPS) STAGE(t + 1, (t + 1) & 1);
        const unsigned short* Ac = &Al[t & 1][0];
        const unsigned short* Bc = &Bl[t & 1][0];
        __builtin_amdgcn_s_setprio(1);
        #pragma unroll
        for (int ks2 = 0; ks2 < 2; ++ks2) {
            int ch = (((ks2 * 4 + kb) ^ sw) << 3);
            bf16x8 a[2];
            #pragma unroll
            for (int mi = 0; mi < 2; ++mi)
                a[mi] = *(const bf16x8*)(Ac + (wv * 32 + mi * 16 + m16) * 64 + ch);
            #pragma unroll
            for (int nb = 0; nb < 5; ++nb) {
                bf16x8 b = *(const bf16x8*)(Bc + (nb * 16 + m16) * 64 + ch);
                #pragma unroll
                for (int mi = 0; mi < 2; ++mi)
                    acc[mi][nb] = __builtin_amdgcn_mfma_f32_16x16x32_bf16(a[mi], b, acc[mi][nb], 0, 0, 0);
            }
        }
        __builtin_amdgcn_s_setprio(0);
        __syncthreads();   // vmcnt(0)+lgkmcnt(0)+barrier: stage(t+1) landed
    }

    float* Po = P + (size_t)bz * BB * DD;
    #pragma unroll
    for (int mi = 0; mi < 2; ++mi)
        #pragma unroll
        for (int nb = 0; nb < 5; ++nb)
            #pragma unroll
            for (int rr = 0; rr < 4; ++rr) {
                int gr = bm * 128 + wv * 32 + mi * 16 + kb * 4 + rr;
                int gc = bn * 80 + nb * 16 + m16;
                Po[(size_t)gr * DD + gc] = acc[mi][nb][rr];
            }
}

// ------ reduce split-K partials + bias, emit bn2 per-column partials -------
__global__ __launch_bounds__(256) void reduce_bn2(const float* __restrict__ P,
                                                  const float* __restrict__ bias2,
                                                  float* __restrict__ out,
                                                  float* __restrict__ part) {
    int blk = blockIdx.x, tid = threadIdx.x;   // RB2 blocks x 16 rows
    int r0 = blk * 16;
    const size_t S = (size_t)BB * DD;
    bool hasb = tid < DD - 256;
    float bia = bias2[tid];
    float bib = hasb ? bias2[256 + tid] : 0.f;
    float s1a = 0.f, s2a = 0.f, s1b = 0.f, s2b = 0.f;
    for (int r = 0; r < 16; ++r) {
        size_t base = (size_t)(r0 + r) * DD;
        float v = P[base + tid] + P[S + base + tid] + P[2 * S + base + tid] + P[3 * S + base + tid] + bia;
        out[base + tid] = v;
        s1a += v; s2a = fmaf(v, v, s2a);
        if (hasb) {
            size_t b2i = base + 256 + tid;
            float u = P[b2i] + P[S + b2i] + P[2 * S + b2i] + P[3 * S + b2i] + bib;
            out[b2i] = u;
            s1b += u; s2b = fmaf(u, u, s2b);
        }
    }
    float* p = part + (size_t)blk * (DD * 2);
    p[tid * 2] = s1a; p[tid * 2 + 1] = s2a;
    if (hasb) { p[(256 + tid) * 2] = s1b; p[(256 + tid) * 2 + 1] = s2b; }
}

__global__ __launch_bounds__(128) void bn2_fin(const float* __restrict__ part,
                                               const float* __restrict__ g2,
                                               const float* __restrict__ b2,
                                               float* __restrict__ sc,
                                               float* __restrict__ sh) {
    __shared__ float red[4];
    int col = blockIdx.x, tid = threadIdx.x;
    float s1 = 0.f, s2 = 0.f;
    for (int t = tid; t < RB2; t += 128) {
        s1 += part[(size_t)t * (DD * 2) + col * 2];
        s2 += part[(size_t)t * (DD * 2) + col * 2 + 1];
    }
    #pragma unroll
    for (int m = 1; m < 64; m <<= 1) { s1 += __shfl_xor(s1, m); s2 += __shfl_xor(s2, m); }
    int wv = tid >> 6;
    if ((tid & 63) == 0) { red[wv] = s1; red[2 + wv] = s2; }
    __syncthreads();
    if (tid == 0) {
        double t1 = (double)red[0] + red[1];
        double t2 = (double)red[2] + red[3];
        double mean = t1 / (double)BB;
        double var = t2 / (double)BB - mean * mean;
        float s = (float)((double)g2[col] / sqrt(var + EPSF));
        sc[col] = s;
        sh[col] = (float)((double)b2[col] - mean * s);
    }
}

__global__ __launch_bounds__(256) void final_k(float* __restrict__ out,
                                               const float* __restrict__ sc,
                                               const float* __restrict__ sh) {
    __shared__ float lsc[DD], lsh[DD];
    int tid = threadIdx.x;
    for (int c = tid; c < DD; c += 256) { lsc[c] = sc[c]; lsh[c] = sh[c]; }
    __syncthreads();
    size_t base = (size_t)blockIdx.x * 4 * DD;
    for (int r = 0; r < 4; ++r)
        for (int c = tid; c < DD; c += 256) {
            size_t i = base + (size_t)r * DD + c;
            float v = fmaf(out[i], lsc[c], lsh[c]);
            out[i] = v > 0.f ? v : 0.f;
        }
}

// ---------------------------------------------------------------------------
extern "C" void kernel_launch(void* const* d_in, const int* in_sizes, int n_in,
                              void* d_out, int out_size, void* d_ws, size_t ws_size,
                              hipStream_t stream) {
    const int* ht      = (const int*)d_in[0];
    const float* UE    = (const float*)d_in[1];
    const float* W_E   = (const float*)d_in[2];
    const float* fc1_w = (const float*)d_in[3];
    const float* fc1_b = (const float*)d_in[4];
    const float* fc_w  = (const float*)d_in[5];
    const float* fc_b  = (const float*)d_in[6];
    const float* bn0_g = (const float*)d_in[7];
    const float* bn0_b = (const float*)d_in[8];
    const float* bn1_g = (const float*)d_in[9];
    const float* bn1_b = (const float*)d_in[10];
    const float* bn2_g = (const float*)d_in[11];
    const float* bn2_b = (const float*)d_in[12];
    float* out = (float*)d_out;

    char* w = (char*)d_ws;
    unsigned short* convb = (unsigned short*)w; w += (size_t)BB * FCLEN * 2;      // 205.5 MB
    unsigned short* Bprep = (unsigned short*)w; w += (size_t)DD * FCLEN * 2;      // 10 MB
    float* chpartT = (float*)w; w += (size_t)2 * OCC * BB * 4;                    // 2.1 MB
    float* bn0p = (float*)w;  w += 640 * 2 * 4;
    float* ab0 = (float*)w;   w += 64;
    float* alphabeta = (float*)w; w += 64 * 4;
    float* bias2 = (float*)w; w += DD * 4;
    float* bn2p = (float*)w;  w += (size_t)RB2 * DD * 2 * 4;
    float* bn2sc = (float*)w; w += DD * 4;
    float* bn2sh = (float*)w; w += DD * 4;
    // split-K partial region (52.4 MB), aliased over head/kbuf/Mbuf (dead by
    // the time fc_gemm_sk runs):
    float* P = (float*)w;     w += (size_t)KSPL * BB * DD * 4;
    float* head = P;                      // 13.1 MB, consumed by conv_k
    float* kbuf = head + (size_t)BB * DD; // 9.4 MB, consumed by conv_k
    float* Mbuf = kbuf + (size_t)BB * RR; // 0.46 MB, consumed by gemm_s1<96>
    (void)ws_size; (void)in_sizes; (void)n_in; (void)out_size;

    prep_M<<<dim3(RR / 16, DD / 16), dim3(16, 16), 0, stream>>>(W_E, fc1_w, Mbuf);
    gemm_s1<80><<<dim3(BB / 64, DD / 80), 256, 0, stream>>>(UE, ht, W_E, nullptr, head, DD, bn0p);
    gemm_s1<96><<<dim3(BB / 64, RR / 96), 256, 0, stream>>>(UE, ht + BB, Mbuf, fc1_b, kbuf, RR, nullptr);
    bn0_fin<<<1, 256, 0, stream>>>(bn0p, bn0_g, bn0_b, ab0);
    conv_k<<<BB, 256, 0, stream>>>(head, kbuf, ab0, convb, chpartT);
    bn1_fin<<<OCC, 256, 0, stream>>>(chpartT, bn1_g, bn1_b, alphabeta);
    prep_fcw<<<DD, 256, 0, stream>>>(fc_w, fc_b, alphabeta, Bprep, bias2);
    fc_gemm_sk<<<dim3(64 * 5 * KSPL), 256, 0, stream>>>(convb, Bprep, P);
    reduce_bn2<<<RB2, 256, 0, stream>>>(P, bias2, out, bn2p);
    bn2_fin<<<DD, 128, 0, stream>>>(bn2p, bn2_g, bn2_b, bn2sc, bn2sh);
    final_k<<<2048, 256, 0, stream>>>(out, bn2sc, bn2sh);
}

// Round 7
// 349.927 us; speedup vs baseline: 2.7537x; 1.0004x over previous
//
#include <hip/hip_runtime.h>

// ---------------------------------------------------------------------------
// HypER pipeline on MI355X. B=8192, D=400, OC=32, FW=9, J=392, R=288,
// FCLEN=12544.
//   M    = W_E @ fc1_w.T            (400x288)      prep_M
//   head = bf16(UE[ht0]) @ bf16(W_E) + bn0 stats   gemm_s1<80> (fused)
//   k    = bf16(UE[ht1]) @ bf16(M) + fc1_b         gemm_s1<96>
//   bn0 finalize -> a0,b0                          bn0_fin
//   conv[b,o,j] -> bf16 convb + per-ch stats       conv_k (reg sliding window)
//   bn1 -> alpha,beta; fold into fc_w              bn1_fin, prep_fcw
//   pre  = convb @ Bprep^T  (split-K=4)            fc_gemm_sk:
//          BM=128 BN=80 dbuf, COUNTED-vmcnt pipeline (T4): own-wait(7|6) +
//          barrier before MFMA, lgkm+barrier after; never vmcnt(0) in loop
//   reduce partials + bias + bn2 partial stats     reduce_bn2 (512 blocks)
//   bn2 finalize + relu                            bn2_fin, final_k
// ---------------------------------------------------------------------------

#define BB   8192
#define DD   400
#define RR   288
#define OCC  32
#define FWW  9
#define JJ   392
#define FCLEN 12544
#define KSPL 4
#define KS   (FCLEN / KSPL)   /* 3136 */
#define KSTEPS (KS / 64)      /* 49 */
#define EPSF 1e-5
#define RB2  512              /* reduce_bn2 blocks */

typedef __attribute__((ext_vector_type(8))) short bf16x8;
typedef __attribute__((ext_vector_type(4))) float f32x4;

__device__ inline unsigned short f2bf(float f) {
    union { float f; unsigned u; } x; x.f = f;
    unsigned r = x.u + 0x7fffu + ((x.u >> 16) & 1u);
    return (unsigned short)(r >> 16);
}

__device__ inline void gload16(const void* g, void* l) {
    __builtin_amdgcn_global_load_lds((const __attribute__((address_space(1))) unsigned int*)g,
                                     (__attribute__((address_space(3))) unsigned int*)l, 16, 0, 0);
}

__device__ inline float block_reduce_256(float v, float* red) {
    #pragma unroll
    for (int m = 1; m < 64; m <<= 1) v += __shfl_xor(v, m);
    int wv = threadIdx.x >> 6;
    if ((threadIdx.x & 63) == 0) red[wv] = v;
    __syncthreads();
    float r = 0.f;
    if (threadIdx.x == 0) r = red[0] + red[1] + red[2] + red[3];
    return r;
}

// ---------------- prep_M: M[i][r] = sum_d W_E[i][d]*fc1_w[r][d] ------------
__global__ __launch_bounds__(256) void prep_M(const float* __restrict__ WE,
                                              const float* __restrict__ f1w,
                                              float* __restrict__ Mout) {
    __shared__ float sA[16][17];
    __shared__ float sB[16][17];
    int tx = threadIdx.x, ty = threadIdx.y;
    int r0 = blockIdx.x * 16, i0 = blockIdx.y * 16;
    float acc = 0.f;
    for (int d0 = 0; d0 < DD; d0 += 16) {
        sA[ty][tx] = WE[(size_t)(i0 + ty) * DD + d0 + tx];
        sB[ty][tx] = f1w[(size_t)(r0 + ty) * DD + d0 + tx];
        __syncthreads();
        #pragma unroll
        for (int dd = 0; dd < 16; ++dd) acc = fmaf(sA[ty][dd], sB[tx][dd], acc);
        __syncthreads();
    }
    Mout[(size_t)(i0 + ty) * RR + r0 + tx] = acc;
}

// ------------- stage-1 gathered GEMM, T14 async-stage pipeline -------------
// Optionally emits per-block partial (sum, sumsq) of outputs for bn0.
template <int BN>
__global__ __launch_bounds__(256) void gemm_s1(const float* __restrict__ A,
                                               const int* __restrict__ idx,
                                               const float* __restrict__ Bm,
                                               const float* __restrict__ bias,
                                               float* __restrict__ C, int N,
                                               float* __restrict__ bn0part) {
    constexpr int BNF = BN / 16;
    constexpr int BCH = 64 * (BN / 4) / 256;   // B float4-chunks per thread
    __shared__ unsigned short Al[64][72];
    __shared__ unsigned short Bl[BN][72];
    __shared__ int ridx[64];
    __shared__ float red[8];
    int tid = threadIdx.x;
    int bm = blockIdx.x, bn = blockIdx.y;
    if (tid < 64) ridx[tid] = idx[bm * 64 + tid];
    int lane = tid & 63, wv = tid >> 6;
    int m16 = lane & 15, kb = lane >> 4;
    f32x4 acc[BNF];
    #pragma unroll
    for (int nb = 0; nb < BNF; ++nb) acc[nb] = (f32x4){0.f, 0.f, 0.f, 0.f};
    __syncthreads();

    float4 av[4];
    float4 bv[BCH];
    auto LOADR = [&](int k0) {
        #pragma unroll
        for (int r = 0; r < 4; ++r) {
            int c = tid + 256 * r;
            int row = c >> 4, kq = c & 15;
            int gk = k0 + kq * 4;
            av[r] = (float4){0.f, 0.f, 0.f, 0.f};
            if (gk < DD) av[r] = *(const float4*)(A + (size_t)ridx[row] * DD + gk);
        }
        #pragma unroll
        for (int r = 0; r < BCH; ++r) {
            int c = tid + 256 * r;
            int kk2 = c / (BN / 4), nq = c % (BN / 4);
            int gk = k0 + kk2;
            bv[r] = (float4){0.f, 0.f, 0.f, 0.f};
            if (gk < DD) bv[r] = *(const float4*)(Bm + (size_t)gk * N + bn * BN + nq * 4);
        }
    };
    auto WRITELDS = [&]() {
        #pragma unroll
        for (int r = 0; r < 4; ++r) {
            int c = tid + 256 * r;
            int row = c >> 4, kq = c & 15;
            ushort4 p;
            p.x = f2bf(av[r].x); p.y = f2bf(av[r].y); p.z = f2bf(av[r].z); p.w = f2bf(av[r].w);
            *(ushort4*)&Al[row][kq * 4] = p;
        }
        #pragma unroll
        for (int r = 0; r < BCH; ++r) {
            int c = tid + 256 * r;
            int kk2 = c / (BN / 4), nq = c % (BN / 4);
            Bl[nq * 4 + 0][kk2] = f2bf(bv[r].x);
            Bl[nq * 4 + 1][kk2] = f2bf(bv[r].y);
            Bl[nq * 4 + 2][kk2] = f2bf(bv[r].z);
            Bl[nq * 4 + 3][kk2] = f2bf(bv[r].w);
        }
    };

    LOADR(0);
    for (int kt = 0; kt < 7; ++kt) {
        WRITELDS();
        __syncthreads();
        if (kt + 1 < 7) LOADR((kt + 1) * 64);   // latency hides under MFMA
        #pragma unroll
        for (int ks = 0; ks < 2; ++ks) {
            bf16x8 a = *(const bf16x8*)&Al[wv * 16 + m16][ks * 32 + kb * 8];
            #pragma unroll
            for (int nb = 0; nb < BNF; ++nb) {
                bf16x8 b = *(const bf16x8*)&Bl[nb * 16 + m16][ks * 32 + kb * 8];
                acc[nb] = __builtin_amdgcn_mfma_f32_16x16x32_bf16(a, b, acc[nb], 0, 0, 0);
            }
        }
        __syncthreads();
    }
    float s1 = 0.f, s2 = 0.f;
    #pragma unroll
    for (int nb = 0; nb < BNF; ++nb)
        #pragma unroll
        for (int rr = 0; rr < 4; ++rr) {
            int gr = bm * 64 + wv * 16 + kb * 4 + rr;
            int gc = bn * BN + nb * 16 + m16;
            float v = acc[nb][rr];
            if (bias) v += bias[gc];
            C[(size_t)gr * N + gc] = v;
            s1 += v; s2 = fmaf(v, v, s2);
        }
    if (bn0part) {
        float t1 = block_reduce_256(s1, red);
        __syncthreads();
        float t2 = block_reduce_256(s2, red);
        if (tid == 0) {
            int pid = bm * gridDim.y + bn;
            bn0part[pid * 2] = t1; bn0part[pid * 2 + 1] = t2;
        }
    }
}

// ---------------- bn0 finalize over 640 block partials ---------------------
__global__ __launch_bounds__(256) void bn0_fin(const float* __restrict__ part,
                                               const float* __restrict__ g,
                                               const float* __restrict__ b,
                                               float* __restrict__ ab0) {
    __shared__ float red[8];
    float s1 = 0.f, s2 = 0.f;
    for (int i = threadIdx.x; i < 640; i += 256) {
        s1 += part[i * 2]; s2 += part[i * 2 + 1];
    }
    float t1 = block_reduce_256(s1, red);
    __syncthreads();
    float t2 = block_reduce_256(s2, red);
    if (threadIdx.x == 0) {
        double n = (double)BB * DD;
        double mean = (double)t1 / n;
        double var = (double)t2 / n - mean * mean;
        float a0 = (float)((double)g[0] / sqrt(var + EPSF));
        float b0 = (float)((double)b[0] - mean * a0);
        ab0[0] = a0; ab0[1] = b0;
    }
}

// ------ per-sample conv: sliding window in regs, wave owns 8 channels ------
__global__ __launch_bounds__(256) void conv_k(const float* __restrict__ head,
                                              const float* __restrict__ kbuf,
                                              const float* __restrict__ ab0,
                                              unsigned short* __restrict__ convb,
                                              float* __restrict__ chpartT) {
    __shared__ float xs[DD];
    __shared__ float ks[RR];
    int b = blockIdx.x, tid = threadIdx.x;
    float a0 = ab0[0], b0 = ab0[1];
    for (int i = tid; i < DD; i += 256) xs[i] = fmaf(head[(size_t)b * DD + i], a0, b0);
    for (int i = tid; i < RR; i += 256) ks[i] = kbuf[(size_t)b * RR + i];
    __syncthreads();
    int lane = tid & 63, wv = tid >> 6;
    unsigned short* orow = convb + (size_t)b * FCLEN;
    float kk[8][FWW];
    #pragma unroll
    for (int oi = 0; oi < 8; ++oi)
        #pragma unroll
        for (int w2 = 0; w2 < FWW; ++w2) kk[oi][w2] = ks[(wv * 8 + oi) * FWW + w2];
    float s1[8], s2[8];
    #pragma unroll
    for (int oi = 0; oi < 8; ++oi) { s1[oi] = 0.f; s2[oi] = 0.f; }
    #pragma unroll
    for (int jt = 0; jt < 2; ++jt) {
        int j0 = jt * 256 + lane * 4;
        if (j0 < JJ) {
            const float4* x4 = (const float4*)xs;
            float4 va = x4[(j0 >> 2)], vb = x4[(j0 >> 2) + 1], vc = x4[(j0 >> 2) + 2];
            float x[12] = {va.x, va.y, va.z, va.w, vb.x, vb.y, vb.z, vb.w, vc.x, vc.y, vc.z, vc.w};
            #pragma unroll
            for (int oi = 0; oi < 8; ++oi) {
                float acc[4];
                #pragma unroll
                for (int q = 0; q < 4; ++q) {
                    float a = 0.f;
                    #pragma unroll
                    for (int w2 = 0; w2 < FWW; ++w2) a = fmaf(x[q + w2], kk[oi][w2], a);
                    acc[q] = a;
                }
                ushort4 p;
                p.x = f2bf(acc[0]); p.y = f2bf(acc[1]); p.z = f2bf(acc[2]); p.w = f2bf(acc[3]);
                *(ushort4*)(orow + (wv * 8 + oi) * JJ + j0) = p;
                #pragma unroll
                for (int q = 0; q < 4; ++q) { s1[oi] += acc[q]; s2[oi] = fmaf(acc[q], acc[q], s2[oi]); }
            }
        }
    }
    #pragma unroll
    for (int oi = 0; oi < 8; ++oi) {
        float a = s1[oi], c = s2[oi];
        #pragma unroll
        for (int m = 1; m < 64; m <<= 1) { a += __shfl_xor(a, m); c += __shfl_xor(c, m); }
        if (lane == 0) {
            int o = wv * 8 + oi;
            chpartT[(size_t)o * BB + b] = a;
            chpartT[(size_t)(OCC + o) * BB + b] = c;
        }
    }
}

__global__ __launch_bounds__(256) void bn1_fin(const float* __restrict__ chpartT,
                                               const float* __restrict__ g1,
                                               const float* __restrict__ b1,
                                               float* __restrict__ alphabeta) {
    __shared__ float red[8];
    int o = blockIdx.x, tid = threadIdx.x;
    float s1 = 0.f, s2 = 0.f;
    for (int t = tid; t < BB; t += 256) {
        s1 += chpartT[(size_t)o * BB + t];
        s2 += chpartT[(size_t)(OCC + o) * BB + t];
    }
    float t1 = block_reduce_256(s1, red);
    __syncthreads();
    float t2 = block_reduce_256(s2, red);
    if (tid == 0) {
        double n = (double)BB * JJ;
        double mean = (double)t1 / n;
        double var = (double)t2 / n - mean * mean;
        float al = (float)((double)g1[o] / sqrt(var + EPSF));
        float be = (float)((double)b1[o] - mean * al);
        alphabeta[o] = al; alphabeta[OCC + o] = be;
    }
}

// ------- fold bn1 into fc_w: Bprep = bf16(fc_w*alpha); bias2 ---------------
__global__ __launch_bounds__(256) void prep_fcw(const float* __restrict__ fc_w,
                                                const float* __restrict__ fc_b,
                                                const float* __restrict__ alphabeta,
                                                unsigned short* __restrict__ Bp,
                                                float* __restrict__ bias2) {
    __shared__ float al[OCC], be[OCC];
    __shared__ float red[8];
    int d = blockIdx.x, tid = threadIdx.x;
    if (tid < OCC) { al[tid] = alphabeta[tid]; be[tid] = alphabeta[OCC + tid]; }
    __syncthreads();
    const float* row = fc_w + (size_t)d * FCLEN;
    unsigned short* orow = Bp + (size_t)d * FCLEN;
    float bacc = 0.f;
    for (int o = 0; o < OCC; ++o) {
        float a = al[o], bb = be[o];
        for (int j = tid; j < JJ; j += 256) {
            float wv = row[o * JJ + j];
            orow[o * JJ + j] = f2bf(wv * a);
            bacc = fmaf(wv, bb, bacc);
        }
    }
    float t = block_reduce_256(bacc, red);
    if (tid == 0) bias2[d] = fc_b[d] + t;
}

// -------- big FC GEMM, split-K=4, BM=128 BN=80, counted-vmcnt dbuf ---------
// T4 handshake per step: STAGE(t+1) -> s_waitcnt vmcnt(own 7|6) -> barrier
// (all waves' stage(t) landed) -> MFMA(t) -> lgkmcnt(0) -> barrier (reads
// done, buffer free). vmcnt never drains to 0 in the steady-state loop.
// global_load_lds + both-sides XOR swizzle; bijective XCD grid swizzle.
__global__ __launch_bounds__(256, 3) void fc_gemm_sk(const unsigned short* __restrict__ A,
                                                     const unsigned short* __restrict__ Bp,
                                                     float* __restrict__ P) {
    __shared__ __align__(16) unsigned short Al[2][128 * 64];   // 2 x 16 KiB
    __shared__ __align__(16) unsigned short Bl[2][80 * 64];    // 2 x 10 KiB
    int tid = threadIdx.x;
    // bijective XCD swizzle: nwg = 1280 = 8 x 160
    int orig = blockIdx.x;
    int wgid = (orig & 7) * 160 + (orig >> 3);
    int bn = wgid % 5;
    int rest = wgid / 5;            // 0..255
    int bm = rest & 63;
    int bz = rest >> 6;
    int lane = tid & 63, wv = tid >> 6;
    int m16 = lane & 15, kb = lane >> 4;
    int srow = lane >> 3, scol = lane & 7;    // staging: (row-in-chunk, 16B slot)
    int sw = m16 & 7;                          // read-side XOR term (row & 7)
    f32x4 acc[2][5];
    #pragma unroll
    for (int mi = 0; mi < 2; ++mi)
        #pragma unroll
        for (int nb = 0; nb < 5; ++nb) acc[mi][nb] = (f32x4){0.f, 0.f, 0.f, 0.f};

    // per-lane pre-swizzled global sources (chunk = 1KB = 8 rows x 64 cols)
    const unsigned short* Asrc = A + (size_t)(bm * 128 + srow) * FCLEN
                                   + (size_t)bz * KS + ((scol ^ srow) << 3);
    const unsigned short* Bsrc = Bp + (size_t)(bn * 80 + srow) * FCLEN
                                   + (size_t)bz * KS + ((scol ^ srow) << 3);

    // 26 chunks: 16 A + 10 B; wave wv takes chunks wv + 4i
    // -> waves 0,1 issue 7 loads; waves 2,3 issue 6.
    auto STAGE = [&](int t, int buf) {
        const size_t koff = (size_t)t * 64;
        #pragma unroll
        for (int i = 0; i < 7; ++i) {
            int c = wv + i * 4;
            if (c < 16) {
                gload16(Asrc + (size_t)c * 8 * FCLEN + koff, &Al[buf][c * 512]);
            } else if (c < 26) {
                int cb = c - 16;
                gload16(Bsrc + (size_t)cb * 8 * FCLEN + koff, &Bl[buf][cb * 512]);
            }
        }
    };

    STAGE(0, 0);
    asm volatile("s_waitcnt vmcnt(0)" ::: "memory");
    __builtin_amdgcn_s_barrier();
    __builtin_amdgcn_sched_barrier(0);

    for (int t = 0; t < KSTEPS; ++t) {
        if (t + 1 < KSTEPS) {
            STAGE(t + 1, (t + 1) & 1);
            // wait for OWN stage(t) loads (older); stage(t+1) stays in flight
            if (wv < 2) asm volatile("s_waitcnt vmcnt(7)" ::: "memory");
            else        asm volatile("s_waitcnt vmcnt(6)" ::: "memory");
        } else {
            asm volatile("s_waitcnt vmcnt(0)" ::: "memory");
        }
        __builtin_amdgcn_s_barrier();      // all waves' stage(t) landed
        __builtin_amdgcn_sched_barrier(0);
        const unsigned short* Ac = &Al[t & 1][0];
        const unsigned short* Bc = &Bl[t & 1][0];
        __builtin_amdgcn_s_setprio(1);
        #pragma unroll
        for (int ks2 = 0; ks2 < 2; ++ks2) {
            int ch = (((ks2 * 4 + kb) ^ sw) << 3);
            bf16x8 a[2];
            #pragma unroll
            for (int mi = 0; mi < 2; ++mi)
                a[mi] = *(const bf16x8*)(Ac + (wv * 32 + mi * 16 + m16) * 64 + ch);
            #pragma unroll
            for (int nb = 0; nb < 5; ++nb) {
                bf16x8 b = *(const bf16x8*)(Bc + (nb * 16 + m16) * 64 + ch);
                #pragma unroll
                for (int mi = 0; mi < 2; ++mi)
                    acc[mi][nb] = __builtin_amdgcn_mfma_f32_16x16x32_bf16(a[mi], b, acc[mi][nb], 0, 0, 0);
            }
        }
        __builtin_amdgcn_s_setprio(0);
        asm volatile("s_waitcnt lgkmcnt(0)" ::: "memory");
        __builtin_amdgcn_sched_barrier(0);
        __builtin_amdgcn_s_barrier();      // reads done -> next overwrite legal
        __builtin_amdgcn_sched_barrier(0);
    }

    float* Po = P + (size_t)bz * BB * DD;
    #pragma unroll
    for (int mi = 0; mi < 2; ++mi)
        #pragma unroll
        for (int nb = 0; nb < 5; ++nb)
            #pragma unroll
            for (int rr = 0; rr < 4; ++rr) {
                int gr = bm * 128 + wv * 32 + mi * 16 + kb * 4 + rr;
                int gc = bn * 80 + nb * 16 + m16;
                Po[(size_t)gr * DD + gc] = acc[mi][nb][rr];
            }
}

// ------ reduce split-K partials + bias, emit bn2 per-column partials -------
__global__ __launch_bounds__(256) void reduce_bn2(const float* __restrict__ P,
                                                  const float* __restrict__ bias2,
                                                  float* __restrict__ out,
                                                  float* __restrict__ part) {
    int blk = blockIdx.x, tid = threadIdx.x;   // RB2 blocks x 16 rows
    int r0 = blk * 16;
    const size_t S = (size_t)BB * DD;
    bool hasb = tid < DD - 256;
    float bia = bias2[tid];
    float bib = hasb ? bias2[256 + tid] : 0.f;
    float s1a = 0.f, s2a = 0.f, s1b = 0.f, s2b = 0.f;
    for (int r = 0; r < 16; ++r) {
        size_t base = (size_t)(r0 + r) * DD;
        float v = P[base + tid] + P[S + base + tid] + P[2 * S + base + tid] + P[3 * S + base + tid] + bia;
        out[base + tid] = v;
        s1a += v; s2a = fmaf(v, v, s2a);
        if (hasb) {
            size_t b2i = base + 256 + tid;
            float u = P[b2i] + P[S + b2i] + P[2 * S + b2i] + P[3 * S + b2i] + bib;
            out[b2i] = u;
            s1b += u; s2b = fmaf(u, u, s2b);
        }
    }
    float* p = part + (size_t)blk * (DD * 2);
    p[tid * 2] = s1a; p[tid * 2 + 1] = s2a;
    if (hasb) { p[(256 + tid) * 2] = s1b; p[(256 + tid) * 2 + 1] = s2b; }
}

__global__ __launch_bounds__(128) void bn2_fin(const float* __restrict__ part,
                                               const float* __restrict__ g2,
                                               const float* __restrict__ b2,
                                               float* __restrict__ sc,
                                               float* __restrict__ sh) {
    __shared__ float red[4];
    int col = blockIdx.x, tid = threadIdx.x;
    float s1 = 0.f, s2 = 0.f;
    for (int t = tid; t < RB2; t += 128) {
        s1 += part[(size_t)t * (DD * 2) + col * 2];
        s2 += part[(size_t)t * (DD * 2) + col * 2 + 1];
    }
    #pragma unroll
    for (int m = 1; m < 64; m <<= 1) { s1 += __shfl_xor(s1, m); s2 += __shfl_xor(s2, m); }
    int wv = tid >> 6;
    if ((tid & 63) == 0) { red[wv] = s1; red[2 + wv] = s2; }
    __syncthreads();
    if (tid == 0) {
        double t1 = (double)red[0] + red[1];
        double t2 = (double)red[2] + red[3];
        double mean = t1 / (double)BB;
        double var = t2 / (double)BB - mean * mean;
        float s = (float)((double)g2[col] / sqrt(var + EPSF));
        sc[col] = s;
        sh[col] = (float)((double)b2[col] - mean * s);
    }
}

__global__ __launch_bounds__(256) void final_k(float* __restrict__ out,
                                               const float* __restrict__ sc,
                                               const float* __restrict__ sh) {
    __shared__ float lsc[DD], lsh[DD];
    int tid = threadIdx.x;
    for (int c = tid; c < DD; c += 256) { lsc[c] = sc[c]; lsh[c] = sh[c]; }
    __syncthreads();
    size_t base = (size_t)blockIdx.x * 4 * DD;
    for (int r = 0; r < 4; ++r)
        for (int c = tid; c < DD; c += 256) {
            size_t i = base + (size_t)r * DD + c;
            float v = fmaf(out[i], lsc[c], lsh[c]);
            out[i] = v > 0.f ? v : 0.f;
        }
}

// ---------------------------------------------------------------------------
extern "C" void kernel_launch(void* const* d_in, const int* in_sizes, int n_in,
                              void* d_out, int out_size, void* d_ws, size_t ws_size,
                              hipStream_t stream) {
    const int* ht      = (const int*)d_in[0];
    const float* UE    = (const float*)d_in[1];
    const float* W_E   = (const float*)d_in[2];
    const float* fc1_w = (const float*)d_in[3];
    const float* fc1_b = (const float*)d_in[4];
    const float* fc_w  = (const float*)d_in[5];
    const float* fc_b  = (const float*)d_in[6];
    const float* bn0_g = (const float*)d_in[7];
    const float* bn0_b = (const float*)d_in[8];
    const float* bn1_g = (const float*)d_in[9];
    const float* bn1_b = (const float*)d_in[10];
    const float* bn2_g = (const float*)d_in[11];
    const float* bn2_b = (const float*)d_in[12];
    float* out = (float*)d_out;

    char* w = (char*)d_ws;
    unsigned short* convb = (unsigned short*)w; w += (size_t)BB * FCLEN * 2;      // 205.5 MB
    unsigned short* Bprep = (unsigned short*)w; w += (size_t)DD * FCLEN * 2;      // 10 MB
    float* chpartT = (float*)w; w += (size_t)2 * OCC * BB * 4;                    // 2.1 MB
    float* bn0p = (float*)w;  w += 640 * 2 * 4;
    float* ab0 = (float*)w;   w += 64;
    float* alphabeta = (float*)w; w += 64 * 4;
    float* bias2 = (float*)w; w += DD * 4;
    float* bn2p = (float*)w;  w += (size_t)RB2 * DD * 2 * 4;
    float* bn2sc = (float*)w; w += DD * 4;
    float* bn2sh = (float*)w; w += DD * 4;
    // split-K partial region (52.4 MB), aliased over head/kbuf/Mbuf (dead by
    // the time fc_gemm_sk runs):
    float* P = (float*)w;     w += (size_t)KSPL * BB * DD * 4;
    float* head = P;                      // 13.1 MB, consumed by conv_k
    float* kbuf = head + (size_t)BB * DD; // 9.4 MB, consumed by conv_k
    float* Mbuf = kbuf + (size_t)BB * RR; // 0.46 MB, consumed by gemm_s1<96>
    (void)ws_size; (void)in_sizes; (void)n_in; (void)out_size;

    prep_M<<<dim3(RR / 16, DD / 16), dim3(16, 16), 0, stream>>>(W_E, fc1_w, Mbuf);
    gemm_s1<80><<<dim3(BB / 64, DD / 80), 256, 0, stream>>>(UE, ht, W_E, nullptr, head, DD, bn0p);
    gemm_s1<96><<<dim3(BB / 64, RR / 96), 256, 0, stream>>>(UE, ht + BB, Mbuf, fc1_b, kbuf, RR, nullptr);
    bn0_fin<<<1, 256, 0, stream>>>(bn0p, bn0_g, bn0_b, ab0);
    conv_k<<<BB, 256, 0, stream>>>(head, kbuf, ab0, convb, chpartT);
    bn1_fin<<<OCC, 256, 0, stream>>>(chpartT, bn1_g, bn1_b, alphabeta);
    prep_fcw<<<DD, 256, 0, stream>>>(fc_w, fc_b, alphabeta, Bprep, bias2);
    fc_gemm_sk<<<dim3(64 * 5 * KSPL), 256, 0, stream>>>(convb, Bprep, P);
    reduce_bn2<<<RB2, 256, 0, stream>>>(P, bias2, out, bn2p);
    bn2_fin<<<DD, 128, 0, stream>>>(bn2p, bn2_g, bn2_b, bn2sc, bn2sh);
    final_k<<<2048, 256, 0, stream>>>(out, bn2sc, bn2sh);
}

// Round 8
// 336.139 us; speedup vs baseline: 2.8667x; 1.0410x over previous
//
#include <hip/hip_runtime.h>

// ---------------------------------------------------------------------------
// HypER pipeline on MI355X. B=8192, D=400, OC=32, FW=9, J=392, R=288,
// FCLEN=12544.
//   M    = W_E @ fc1_w.T            (400x288)      prep_M
//   head = bf16(UE[ht0]) @ bf16(W_E) + bn0 stats   gemm_s1<80> (fused)
//   k    = bf16(UE[ht1]) @ bf16(M) + fc1_b         gemm_s1<96>
//   bn0 finalize -> a0,b0                          bn0_fin
//   conv[b,o,j] -> bf16 convb + per-ch stats       conv_k (reg sliding window)
//   bn1 -> alpha,beta; fold into fc_w              bn1_fin, prep_fcw
//   pre  = convb @ Bprep^T  (split-K=4)            fc_gemm_sk:
//          BM=256 BN=80, 4 waves x (64x80), single-buffer LDS 42KB,
//          global_load_lds + both-sides XOR swizzle, 3 blocks/CU,
//          bijective XCD grid swizzle (640 = 8 x 80)
//   reduce partials + bias + bn2 partial stats     reduce_bn2 (512 blocks)
//   bn2 finalize + relu                            bn2_fin, final_k
// ---------------------------------------------------------------------------

#define BB   8192
#define DD   400
#define RR   288
#define OCC  32
#define FWW  9
#define JJ   392
#define FCLEN 12544
#define KSPL 4
#define KS   (FCLEN / KSPL)   /* 3136 */
#define KSTEPS (KS / 64)      /* 49 */
#define EPSF 1e-5
#define RB2  512              /* reduce_bn2 blocks */

typedef __attribute__((ext_vector_type(8))) short bf16x8;
typedef __attribute__((ext_vector_type(4))) float f32x4;

__device__ inline unsigned short f2bf(float f) {
    union { float f; unsigned u; } x; x.f = f;
    unsigned r = x.u + 0x7fffu + ((x.u >> 16) & 1u);
    return (unsigned short)(r >> 16);
}

__device__ inline void gload16(const void* g, void* l) {
    __builtin_amdgcn_global_load_lds((const __attribute__((address_space(1))) unsigned int*)g,
                                     (__attribute__((address_space(3))) unsigned int*)l, 16, 0, 0);
}

__device__ inline float block_reduce_256(float v, float* red) {
    #pragma unroll
    for (int m = 1; m < 64; m <<= 1) v += __shfl_xor(v, m);
    int wv = threadIdx.x >> 6;
    if ((threadIdx.x & 63) == 0) red[wv] = v;
    __syncthreads();
    float r = 0.f;
    if (threadIdx.x == 0) r = red[0] + red[1] + red[2] + red[3];
    return r;
}

// ---------------- prep_M: M[i][r] = sum_d W_E[i][d]*fc1_w[r][d] ------------
__global__ __launch_bounds__(256) void prep_M(const float* __restrict__ WE,
                                              const float* __restrict__ f1w,
                                              float* __restrict__ Mout) {
    __shared__ float sA[16][17];
    __shared__ float sB[16][17];
    int tx = threadIdx.x, ty = threadIdx.y;
    int r0 = blockIdx.x * 16, i0 = blockIdx.y * 16;
    float acc = 0.f;
    for (int d0 = 0; d0 < DD; d0 += 16) {
        sA[ty][tx] = WE[(size_t)(i0 + ty) * DD + d0 + tx];
        sB[ty][tx] = f1w[(size_t)(r0 + ty) * DD + d0 + tx];
        __syncthreads();
        #pragma unroll
        for (int dd = 0; dd < 16; ++dd) acc = fmaf(sA[ty][dd], sB[tx][dd], acc);
        __syncthreads();
    }
    Mout[(size_t)(i0 + ty) * RR + r0 + tx] = acc;
}

// ------------- stage-1 gathered GEMM, T14 async-stage pipeline -------------
// Optionally emits per-block partial (sum, sumsq) of outputs for bn0.
template <int BN>
__global__ __launch_bounds__(256) void gemm_s1(const float* __restrict__ A,
                                               const int* __restrict__ idx,
                                               const float* __restrict__ Bm,
                                               const float* __restrict__ bias,
                                               float* __restrict__ C, int N,
                                               float* __restrict__ bn0part) {
    constexpr int BNF = BN / 16;
    constexpr int BCH = 64 * (BN / 4) / 256;   // B float4-chunks per thread
    __shared__ unsigned short Al[64][72];
    __shared__ unsigned short Bl[BN][72];
    __shared__ int ridx[64];
    __shared__ float red[8];
    int tid = threadIdx.x;
    int bm = blockIdx.x, bn = blockIdx.y;
    if (tid < 64) ridx[tid] = idx[bm * 64 + tid];
    int lane = tid & 63, wv = tid >> 6;
    int m16 = lane & 15, kb = lane >> 4;
    f32x4 acc[BNF];
    #pragma unroll
    for (int nb = 0; nb < BNF; ++nb) acc[nb] = (f32x4){0.f, 0.f, 0.f, 0.f};
    __syncthreads();

    float4 av[4];
    float4 bv[BCH];
    auto LOADR = [&](int k0) {
        #pragma unroll
        for (int r = 0; r < 4; ++r) {
            int c = tid + 256 * r;
            int row = c >> 4, kq = c & 15;
            int gk = k0 + kq * 4;
            av[r] = (float4){0.f, 0.f, 0.f, 0.f};
            if (gk < DD) av[r] = *(const float4*)(A + (size_t)ridx[row] * DD + gk);
        }
        #pragma unroll
        for (int r = 0; r < BCH; ++r) {
            int c = tid + 256 * r;
            int kk2 = c / (BN / 4), nq = c % (BN / 4);
            int gk = k0 + kk2;
            bv[r] = (float4){0.f, 0.f, 0.f, 0.f};
            if (gk < DD) bv[r] = *(const float4*)(Bm + (size_t)gk * N + bn * BN + nq * 4);
        }
    };
    auto WRITELDS = [&]() {
        #pragma unroll
        for (int r = 0; r < 4; ++r) {
            int c = tid + 256 * r;
            int row = c >> 4, kq = c & 15;
            ushort4 p;
            p.x = f2bf(av[r].x); p.y = f2bf(av[r].y); p.z = f2bf(av[r].z); p.w = f2bf(av[r].w);
            *(ushort4*)&Al[row][kq * 4] = p;
        }
        #pragma unroll
        for (int r = 0; r < BCH; ++r) {
            int c = tid + 256 * r;
            int kk2 = c / (BN / 4), nq = c % (BN / 4);
            Bl[nq * 4 + 0][kk2] = f2bf(bv[r].x);
            Bl[nq * 4 + 1][kk2] = f2bf(bv[r].y);
            Bl[nq * 4 + 2][kk2] = f2bf(bv[r].z);
            Bl[nq * 4 + 3][kk2] = f2bf(bv[r].w);
        }
    };

    LOADR(0);
    for (int kt = 0; kt < 7; ++kt) {
        WRITELDS();
        __syncthreads();
        if (kt + 1 < 7) LOADR((kt + 1) * 64);   // latency hides under MFMA
        #pragma unroll
        for (int ks = 0; ks < 2; ++ks) {
            bf16x8 a = *(const bf16x8*)&Al[wv * 16 + m16][ks * 32 + kb * 8];
            #pragma unroll
            for (int nb = 0; nb < BNF; ++nb) {
                bf16x8 b = *(const bf16x8*)&Bl[nb * 16 + m16][ks * 32 + kb * 8];
                acc[nb] = __builtin_amdgcn_mfma_f32_16x16x32_bf16(a, b, acc[nb], 0, 0, 0);
            }
        }
        __syncthreads();
    }
    float s1 = 0.f, s2 = 0.f;
    #pragma unroll
    for (int nb = 0; nb < BNF; ++nb)
        #pragma unroll
        for (int rr = 0; rr < 4; ++rr) {
            int gr = bm * 64 + wv * 16 + kb * 4 + rr;
            int gc = bn * BN + nb * 16 + m16;
            float v = acc[nb][rr];
            if (bias) v += bias[gc];
            C[(size_t)gr * N + gc] = v;
            s1 += v; s2 = fmaf(v, v, s2);
        }
    if (bn0part) {
        float t1 = block_reduce_256(s1, red);
        __syncthreads();
        float t2 = block_reduce_256(s2, red);
        if (tid == 0) {
            int pid = bm * gridDim.y + bn;
            bn0part[pid * 2] = t1; bn0part[pid * 2 + 1] = t2;
        }
    }
}

// ---------------- bn0 finalize over 640 block partials ---------------------
__global__ __launch_bounds__(256) void bn0_fin(const float* __restrict__ part,
                                               const float* __restrict__ g,
                                               const float* __restrict__ b,
                                               float* __restrict__ ab0) {
    __shared__ float red[8];
    float s1 = 0.f, s2 = 0.f;
    for (int i = threadIdx.x; i < 640; i += 256) {
        s1 += part[i * 2]; s2 += part[i * 2 + 1];
    }
    float t1 = block_reduce_256(s1, red);
    __syncthreads();
    float t2 = block_reduce_256(s2, red);
    if (threadIdx.x == 0) {
        double n = (double)BB * DD;
        double mean = (double)t1 / n;
        double var = (double)t2 / n - mean * mean;
        float a0 = (float)((double)g[0] / sqrt(var + EPSF));
        float b0 = (float)((double)b[0] - mean * a0);
        ab0[0] = a0; ab0[1] = b0;
    }
}

// ------ per-sample conv: sliding window in regs, wave owns 8 channels ------
__global__ __launch_bounds__(256) void conv_k(const float* __restrict__ head,
                                              const float* __restrict__ kbuf,
                                              const float* __restrict__ ab0,
                                              unsigned short* __restrict__ convb,
                                              float* __restrict__ chpartT) {
    __shared__ float xs[DD];
    __shared__ float ks[RR];
    int b = blockIdx.x, tid = threadIdx.x;
    float a0 = ab0[0], b0 = ab0[1];
    for (int i = tid; i < DD; i += 256) xs[i] = fmaf(head[(size_t)b * DD + i], a0, b0);
    for (int i = tid; i < RR; i += 256) ks[i] = kbuf[(size_t)b * RR + i];
    __syncthreads();
    int lane = tid & 63, wv = tid >> 6;
    unsigned short* orow = convb + (size_t)b * FCLEN;
    float kk[8][FWW];
    #pragma unroll
    for (int oi = 0; oi < 8; ++oi)
        #pragma unroll
        for (int w2 = 0; w2 < FWW; ++w2) kk[oi][w2] = ks[(wv * 8 + oi) * FWW + w2];
    float s1[8], s2[8];
    #pragma unroll
    for (int oi = 0; oi < 8; ++oi) { s1[oi] = 0.f; s2[oi] = 0.f; }
    #pragma unroll
    for (int jt = 0; jt < 2; ++jt) {
        int j0 = jt * 256 + lane * 4;
        if (j0 < JJ) {
            const float4* x4 = (const float4*)xs;
            float4 va = x4[(j0 >> 2)], vb = x4[(j0 >> 2) + 1], vc = x4[(j0 >> 2) + 2];
            float x[12] = {va.x, va.y, va.z, va.w, vb.x, vb.y, vb.z, vb.w, vc.x, vc.y, vc.z, vc.w};
            #pragma unroll
            for (int oi = 0; oi < 8; ++oi) {
                float acc[4];
                #pragma unroll
                for (int q = 0; q < 4; ++q) {
                    float a = 0.f;
                    #pragma unroll
                    for (int w2 = 0; w2 < FWW; ++w2) a = fmaf(x[q + w2], kk[oi][w2], a);
                    acc[q] = a;
                }
                ushort4 p;
                p.x = f2bf(acc[0]); p.y = f2bf(acc[1]); p.z = f2bf(acc[2]); p.w = f2bf(acc[3]);
                *(ushort4*)(orow + (wv * 8 + oi) * JJ + j0) = p;
                #pragma unroll
                for (int q = 0; q < 4; ++q) { s1[oi] += acc[q]; s2[oi] = fmaf(acc[q], acc[q], s2[oi]); }
            }
        }
    }
    #pragma unroll
    for (int oi = 0; oi < 8; ++oi) {
        float a = s1[oi], c = s2[oi];
        #pragma unroll
        for (int m = 1; m < 64; m <<= 1) { a += __shfl_xor(a, m); c += __shfl_xor(c, m); }
        if (lane == 0) {
            int o = wv * 8 + oi;
            chpartT[(size_t)o * BB + b] = a;
            chpartT[(size_t)(OCC + o) * BB + b] = c;
        }
    }
}

__global__ __launch_bounds__(256) void bn1_fin(const float* __restrict__ chpartT,
                                               const float* __restrict__ g1,
                                               const float* __restrict__ b1,
                                               float* __restrict__ alphabeta) {
    __shared__ float red[8];
    int o = blockIdx.x, tid = threadIdx.x;
    float s1 = 0.f, s2 = 0.f;
    for (int t = tid; t < BB; t += 256) {
        s1 += chpartT[(size_t)o * BB + t];
        s2 += chpartT[(size_t)(OCC + o) * BB + t];
    }
    float t1 = block_reduce_256(s1, red);
    __syncthreads();
    float t2 = block_reduce_256(s2, red);
    if (tid == 0) {
        double n = (double)BB * JJ;
        double mean = (double)t1 / n;
        double var = (double)t2 / n - mean * mean;
        float al = (float)((double)g1[o] / sqrt(var + EPSF));
        float be = (float)((double)b1[o] - mean * al);
        alphabeta[o] = al; alphabeta[OCC + o] = be;
    }
}

// ------- fold bn1 into fc_w: Bprep = bf16(fc_w*alpha); bias2 ---------------
__global__ __launch_bounds__(256) void prep_fcw(const float* __restrict__ fc_w,
                                                const float* __restrict__ fc_b,
                                                const float* __restrict__ alphabeta,
                                                unsigned short* __restrict__ Bp,
                                                float* __restrict__ bias2) {
    __shared__ float al[OCC], be[OCC];
    __shared__ float red[8];
    int d = blockIdx.x, tid = threadIdx.x;
    if (tid < OCC) { al[tid] = alphabeta[tid]; be[tid] = alphabeta[OCC + tid]; }
    __syncthreads();
    const float* row = fc_w + (size_t)d * FCLEN;
    unsigned short* orow = Bp + (size_t)d * FCLEN;
    float bacc = 0.f;
    for (int o = 0; o < OCC; ++o) {
        float a = al[o], bb = be[o];
        for (int j = tid; j < JJ; j += 256) {
            float wv = row[o * JJ + j];
            orow[o * JJ + j] = f2bf(wv * a);
            bacc = fmaf(wv, bb, bacc);
        }
    }
    float t = block_reduce_256(bacc, red);
    if (tid == 0) bias2[d] = fc_b[d] + t;
}

// -------- big FC GEMM, split-K=4, BM=256 BN=80, 4 waves x (64x80) ----------
// R5 structure (best measured): single-buffer LDS 42KB -> 3 blocks/CU,
// global_load_lds + both-sides XOR swizzle, simple barrier loop.
// + bijective XCD swizzle over the flat 640-block grid (640 = 8 x 80).
__global__ __launch_bounds__(256, 3) void fc_gemm_sk(const unsigned short* __restrict__ A,
                                                     const unsigned short* __restrict__ Bp,
                                                     float* __restrict__ P) {
    __shared__ __align__(16) unsigned short Al[256 * 64];   // 32 KiB, 32 chunks
    __shared__ __align__(16) unsigned short Bl[80 * 64];    // 10 KiB, 10 chunks
    int tid = threadIdx.x;
    // bijective XCD swizzle: nwg = 640 = 8 x 80; consecutive swizzled ids on
    // one XCD share the same (bm,bz) A-panel (bn varies fastest) -> L2 reuse.
    int orig = blockIdx.x;
    int wgid = (orig & 7) * 80 + (orig >> 3);
    int bn = wgid % 5;
    int rest = wgid / 5;            // 0..127
    int bm = rest & 31;
    int bz = rest >> 5;             // 0..3
    int lane = tid & 63, wv = tid >> 6;
    int m16 = lane & 15, kb = lane >> 4;
    int srow = lane >> 3, scol = lane & 7;    // staging lane -> (row-in-chunk, 16B slot)
    int sw = m16 & 7;                          // read-side XOR term (row & 7)
    f32x4 acc[4][5];
    #pragma unroll
    for (int mi = 0; mi < 4; ++mi)
        #pragma unroll
        for (int nb = 0; nb < 5; ++nb) acc[mi][nb] = (f32x4){0.f, 0.f, 0.f, 0.f};

    // per-lane pre-swizzled global sources (chunk = 1KB = 8 rows x 64 cols)
    const unsigned short* Asrc = A + (size_t)(bm * 256 + srow) * FCLEN
                                   + (size_t)bz * KS + ((scol ^ srow) << 3);
    const unsigned short* Bsrc = Bp + (size_t)(bn * 80 + srow) * FCLEN
                                   + (size_t)bz * KS + ((scol ^ srow) << 3);

    for (int kt = 0; kt < KSTEPS; ++kt) {
        const size_t koff = (size_t)kt * 64;
        // 42 chunks total: 32 A + 10 B, wave wv takes chunks wv+4i
        #pragma unroll
        for (int i = 0; i < 11; ++i) {
            int c = wv + i * 4;
            if (c < 32) {
                gload16(Asrc + (size_t)c * 8 * FCLEN + koff, Al + c * 512);
            } else if (c < 42) {
                int cb = c - 32;
                gload16(Bsrc + (size_t)cb * 8 * FCLEN + koff, Bl + cb * 512);
            }
        }
        __syncthreads();
        #pragma unroll
        for (int ks2 = 0; ks2 < 2; ++ks2) {
            int ch = (((ks2 * 4 + kb) ^ sw) << 3);
            bf16x8 a[4];
            #pragma unroll
            for (int mi = 0; mi < 4; ++mi)
                a[mi] = *(const bf16x8*)(Al + (wv * 64 + mi * 16 + m16) * 64 + ch);
            #pragma unroll
            for (int nb = 0; nb < 5; ++nb) {
                bf16x8 b = *(const bf16x8*)(Bl + (nb * 16 + m16) * 64 + ch);
                #pragma unroll
                for (int mi = 0; mi < 4; ++mi)
                    acc[mi][nb] = __builtin_amdgcn_mfma_f32_16x16x32_bf16(a[mi], b, acc[mi][nb], 0, 0, 0);
            }
        }
        __syncthreads();
    }

    float* Po = P + (size_t)bz * BB * DD;
    #pragma unroll
    for (int mi = 0; mi < 4; ++mi)
        #pragma unroll
        for (int nb = 0; nb < 5; ++nb)
            #pragma unroll
            for (int rr = 0; rr < 4; ++rr) {
                int gr = bm * 256 + wv * 64 + mi * 16 + kb * 4 + rr;
                int gc = bn * 80 + nb * 16 + m16;
                Po[(size_t)gr * DD + gc] = acc[mi][nb][rr];
            }
}

// ------ reduce split-K partials + bias, emit bn2 per-column partials -------
__global__ __launch_bounds__(256) void reduce_bn2(const float* __restrict__ P,
                                                  const float* __restrict__ bias2,
                                                  float* __restrict__ out,
                                                  float* __restrict__ part) {
    int blk = blockIdx.x, tid = threadIdx.x;   // RB2 blocks x 16 rows
    int r0 = blk * 16;
    const size_t S = (size_t)BB * DD;
    bool hasb = tid < DD - 256;
    float bia = bias2[tid];
    float bib = hasb ? bias2[256 + tid] : 0.f;
    float s1a = 0.f, s2a = 0.f, s1b = 0.f, s2b = 0.f;
    for (int r = 0; r < 16; ++r) {
        size_t base = (size_t)(r0 + r) * DD;
        float v = P[base + tid] + P[S + base + tid] + P[2 * S + base + tid] + P[3 * S + base + tid] + bia;
        out[base + tid] = v;
        s1a += v; s2a = fmaf(v, v, s2a);
        if (hasb) {
            size_t b2i = base + 256 + tid;
            float u = P[b2i] + P[S + b2i] + P[2 * S + b2i] + P[3 * S + b2i] + bib;
            out[b2i] = u;
            s1b += u; s2b = fmaf(u, u, s2b);
        }
    }
    float* p = part + (size_t)blk * (DD * 2);
    p[tid * 2] = s1a; p[tid * 2 + 1] = s2a;
    if (hasb) { p[(256 + tid) * 2] = s1b; p[(256 + tid) * 2 + 1] = s2b; }
}

__global__ __launch_bounds__(128) void bn2_fin(const float* __restrict__ part,
                                               const float* __restrict__ g2,
                                               const float* __restrict__ b2,
                                               float* __restrict__ sc,
                                               float* __restrict__ sh) {
    __shared__ float red[4];
    int col = blockIdx.x, tid = threadIdx.x;
    float s1 = 0.f, s2 = 0.f;
    for (int t = tid; t < RB2; t += 128) {
        s1 += part[(size_t)t * (DD * 2) + col * 2];
        s2 += part[(size_t)t * (DD * 2) + col * 2 + 1];
    }
    #pragma unroll
    for (int m = 1; m < 64; m <<= 1) { s1 += __shfl_xor(s1, m); s2 += __shfl_xor(s2, m); }
    int wv = tid >> 6;
    if ((tid & 63) == 0) { red[wv] = s1; red[2 + wv] = s2; }
    __syncthreads();
    if (tid == 0) {
        double t1 = (double)red[0] + red[1];
        double t2 = (double)red[2] + red[3];
        double mean = t1 / (double)BB;
        double var = t2 / (double)BB - mean * mean;
        float s = (float)((double)g2[col] / sqrt(var + EPSF));
        sc[col] = s;
        sh[col] = (float)((double)b2[col] - mean * s);
    }
}

__global__ __launch_bounds__(256) void final_k(float* __restrict__ out,
                                               const float* __restrict__ sc,
                                               const float* __restrict__ sh) {
    __shared__ float lsc[DD], lsh[DD];
    int tid = threadIdx.x;
    for (int c = tid; c < DD; c += 256) { lsc[c] = sc[c]; lsh[c] = sh[c]; }
    __syncthreads();
    size_t base = (size_t)blockIdx.x * 4 * DD;
    for (int r = 0; r < 4; ++r)
        for (int c = tid; c < DD; c += 256) {
            size_t i = base + (size_t)r * DD + c;
            float v = fmaf(out[i], lsc[c], lsh[c]);
            out[i] = v > 0.f ? v : 0.f;
        }
}

// ---------------------------------------------------------------------------
extern "C" void kernel_launch(void* const* d_in, const int* in_sizes, int n_in,
                              void* d_out, int out_size, void* d_ws, size_t ws_size,
                              hipStream_t stream) {
    const int* ht      = (const int*)d_in[0];
    const float* UE    = (const float*)d_in[1];
    const float* W_E   = (const float*)d_in[2];
    const float* fc1_w = (const float*)d_in[3];
    const float* fc1_b = (const float*)d_in[4];
    const float* fc_w  = (const float*)d_in[5];
    const float* fc_b  = (const float*)d_in[6];
    const float* bn0_g = (const float*)d_in[7];
    const float* bn0_b = (const float*)d_in[8];
    const float* bn1_g = (const float*)d_in[9];
    const float* bn1_b = (const float*)d_in[10];
    const float* bn2_g = (const float*)d_in[11];
    const float* bn2_b = (const float*)d_in[12];
    float* out = (float*)d_out;

    char* w = (char*)d_ws;
    unsigned short* convb = (unsigned short*)w; w += (size_t)BB * FCLEN * 2;      // 205.5 MB
    unsigned short* Bprep = (unsigned short*)w; w += (size_t)DD * FCLEN * 2;      // 10 MB
    float* chpartT = (float*)w; w += (size_t)2 * OCC * BB * 4;                    // 2.1 MB
    float* bn0p = (float*)w;  w += 640 * 2 * 4;
    float* ab0 = (float*)w;   w += 64;
    float* alphabeta = (float*)w; w += 64 * 4;
    float* bias2 = (float*)w; w += DD * 4;
    float* bn2p = (float*)w;  w += (size_t)RB2 * DD * 2 * 4;
    float* bn2sc = (float*)w; w += DD * 4;
    float* bn2sh = (float*)w; w += DD * 4;
    // split-K partial region (52.4 MB), aliased over head/kbuf/Mbuf (dead by
    // the time fc_gemm_sk runs):
    float* P = (float*)w;     w += (size_t)KSPL * BB * DD * 4;
    float* head = P;                      // 13.1 MB, consumed by conv_k
    float* kbuf = head + (size_t)BB * DD; // 9.4 MB, consumed by conv_k
    float* Mbuf = kbuf + (size_t)BB * RR; // 0.46 MB, consumed by gemm_s1<96>
    (void)ws_size; (void)in_sizes; (void)n_in; (void)out_size;

    prep_M<<<dim3(RR / 16, DD / 16), dim3(16, 16), 0, stream>>>(W_E, fc1_w, Mbuf);
    gemm_s1<80><<<dim3(BB / 64, DD / 80), 256, 0, stream>>>(UE, ht, W_E, nullptr, head, DD, bn0p);
    gemm_s1<96><<<dim3(BB / 64, RR / 96), 256, 0, stream>>>(UE, ht + BB, Mbuf, fc1_b, kbuf, RR, nullptr);
    bn0_fin<<<1, 256, 0, stream>>>(bn0p, bn0_g, bn0_b, ab0);
    conv_k<<<BB, 256, 0, stream>>>(head, kbuf, ab0, convb, chpartT);
    bn1_fin<<<OCC, 256, 0, stream>>>(chpartT, bn1_g, bn1_b, alphabeta);
    prep_fcw<<<DD, 256, 0, stream>>>(fc_w, fc_b, alphabeta, Bprep, bias2);
    fc_gemm_sk<<<dim3(32 * 5 * KSPL), 256, 0, stream>>>(convb, Bprep, P);
    reduce_bn2<<<RB2, 256, 0, stream>>>(P, bias2, out, bn2p);
    bn2_fin<<<DD, 128, 0, stream>>>(bn2p, bn2_g, bn2_b, bn2sc, bn2sh);
    final_k<<<2048, 256, 0, stream>>>(out, bn2sc, bn2sh);
}